// Round 3
// baseline (626.630 us; speedup 1.0000x reference)
//
#include <hip/hip_runtime.h>

#define NH    8
#define NLVL  3
#define NP    4
#define HD    32
#define EMBED 256

constexpr int LTOT = 13125;   // 100*100 + 50*50 + 25*25
constexpr int BQ   = 4;
constexpr int NQ   = 300;
constexpr int NK   = 17;
constexpr int LQ   = NQ * NK; // 5100

// ---------------------------------------------------------------------------
// GEMM: C[M,N] = A[M,K] @ W[N,K]^T + bias   (optional per-row zero mask)
// 128x128 tile, BK=16, 256 threads, 8x8 per thread (split 4+4 fragments to
// avoid the 4-way LDS bank conflict of a contiguous 8-wide footprint).
// Thread (ty=tid>>4, tx=tid&15) owns rows {ty*4+i, 64+ty*4+i} and
// cols {tx*4+j, 64+tx*4+j}, i,j in 0..3.
// ---------------------------------------------------------------------------
__global__ __launch_bounds__(256)
void gemm_bt(const float* __restrict__ A, const float* __restrict__ W,
             const float* __restrict__ bias, float* __restrict__ C,
             int M, int N, int K, const unsigned char* __restrict__ rowmask)
{
    __shared__ float As[16][128];
    __shared__ float Bs[16][128];

    const int tid  = threadIdx.x;
    const int row0 = blockIdx.y * 128;
    const int col0 = blockIdx.x * 128;
    const int ty   = tid >> 4;          // 0..15
    const int tx   = tid & 15;          // 0..15

    const int lr = tid >> 1;            // 0..127 (tile row for loads)
    const int lk = (tid & 1) * 8;       // 0 or 8 (k sub-offset)

    float acc[8][8];
#pragma unroll
    for (int i = 0; i < 8; ++i)
#pragma unroll
        for (int j = 0; j < 8; ++j) acc[i][j] = 0.f;

    for (int k0 = 0; k0 < K; k0 += 16) {
        // ---- stage A/B tiles (transposed to k-major) ----
        {
            const int grow = row0 + lr;
            float4 va0 = make_float4(0.f, 0.f, 0.f, 0.f), va1 = va0;
            if (grow < M) {
                const float* ap = A + (size_t)grow * K + k0 + lk;
                va0 = *reinterpret_cast<const float4*>(ap);
                va1 = *reinterpret_cast<const float4*>(ap + 4);
            }
            As[lk + 0][lr] = va0.x; As[lk + 1][lr] = va0.y;
            As[lk + 2][lr] = va0.z; As[lk + 3][lr] = va0.w;
            As[lk + 4][lr] = va1.x; As[lk + 5][lr] = va1.y;
            As[lk + 6][lr] = va1.z; As[lk + 7][lr] = va1.w;

            const int gcol = col0 + lr;
            float4 vb0 = make_float4(0.f, 0.f, 0.f, 0.f), vb1 = vb0;
            if (gcol < N) {
                const float* wp = W + (size_t)gcol * K + k0 + lk;
                vb0 = *reinterpret_cast<const float4*>(wp);
                vb1 = *reinterpret_cast<const float4*>(wp + 4);
            }
            Bs[lk + 0][lr] = vb0.x; Bs[lk + 1][lr] = vb0.y;
            Bs[lk + 2][lr] = vb0.z; Bs[lk + 3][lr] = vb0.w;
            Bs[lk + 4][lr] = vb1.x; Bs[lk + 5][lr] = vb1.y;
            Bs[lk + 6][lr] = vb1.z; Bs[lk + 7][lr] = vb1.w;
        }
        __syncthreads();

#pragma unroll
        for (int kk = 0; kk < 16; ++kk) {
            float a[8], b[8];
            *reinterpret_cast<float4*>(&a[0]) =
                *reinterpret_cast<const float4*>(&As[kk][ty * 4]);
            *reinterpret_cast<float4*>(&a[4]) =
                *reinterpret_cast<const float4*>(&As[kk][64 + ty * 4]);
            *reinterpret_cast<float4*>(&b[0]) =
                *reinterpret_cast<const float4*>(&Bs[kk][tx * 4]);
            *reinterpret_cast<float4*>(&b[4]) =
                *reinterpret_cast<const float4*>(&Bs[kk][64 + tx * 4]);
#pragma unroll
            for (int i = 0; i < 8; ++i)
#pragma unroll
                for (int j = 0; j < 8; ++j)
                    acc[i][j] = fmaf(a[i], b[j], acc[i][j]);
        }
        __syncthreads();
    }

    // ---- epilogue: per thread 8 rows x 2 float4 column-chunks ----
#pragma unroll
    for (int i = 0; i < 8; ++i) {
        const int r = row0 + ty * 4 + (i & 3) + (i >> 2) * 64;
        if (r >= M) continue;
        const float keep = (rowmask && rowmask[r]) ? 0.f : 1.f;
#pragma unroll
        for (int jj = 0; jj < 2; ++jj) {
            const int cc = col0 + tx * 4 + jj * 64;
            if (cc < N) {
                float4 o;
                o.x = (acc[i][jj * 4 + 0] + (bias ? bias[cc + 0] : 0.f)) * keep;
                o.y = (acc[i][jj * 4 + 1] + (bias ? bias[cc + 1] : 0.f)) * keep;
                o.z = (acc[i][jj * 4 + 2] + (bias ? bias[cc + 2] : 0.f)) * keep;
                o.w = (acc[i][jj * 4 + 3] + (bias ? bias[cc + 3] : 0.f)) * keep;
                *reinterpret_cast<float4*>(C + (size_t)r * N + cc) = o;
            }
        }
    }
}

// ---------------------------------------------------------------------------
// Fused softmax + bilinear sampling + head-weighted accumulation.
// 256 threads = 4 groups of 64; each group handles one (b,lq).
// Thread in group: head h = t>>3, channel quad c4 = (t&7)*4 -> float4 math.
// Branch-free border handling: clamp indices, zero the corner weight.
// ---------------------------------------------------------------------------
__global__ __launch_bounds__(256)
void msda_sample(const float* __restrict__ v,     // [B][L][256]
                 const float* __restrict__ off,   // [B*LQ][384]
                 const float* __restrict__ aw,    // [B*LQ][96]
                 const float* __restrict__ refl,  // [B][NQ][NL][NK][2]
                 const float* __restrict__ refr,
                 float* __restrict__ out_pre)     // [B*LQ][256]
{
    const int g   = threadIdx.x >> 6;     // group 0..3
    const int t   = threadIdx.x & 63;     // lane in group
    const int bq  = blockIdx.x * 4 + g;
    const int b   = bq / LQ;
    const int lqi = bq - b * LQ;
    const int iq  = lqi / NK;
    const int ik  = lqi - iq * NK;

    __shared__ float s_off[4][384];
    __shared__ float s_aw[4][96];
    __shared__ float s_ref[4][NLVL][4];   // lx, ly, rx, ry

    {
        const float* offp = off + (size_t)bq * 384;
        for (int i = t; i < 384; i += 64) s_off[g][i] = offp[i];
        const float* awp = aw + (size_t)bq * 96;
        for (int i = t; i < 96; i += 64) s_aw[g][i] = awp[i];
        if (t < 12) {
            const int nl = t >> 2, comp = t & 3;
            const float* rp = (comp < 2) ? refl : refr;
            s_ref[g][nl][comp] =
                rp[((((size_t)b * NQ + iq) * NLVL + nl) * NK + ik) * 2 + (comp & 1)];
        }
    }
    __syncthreads();

    const int h  = t >> 3;          // 0..7
    const int c4 = (t & 7) * 4;     // 0,4,...,28

    // softmax over the 12 (nl, p) logits of this head
    float w12[12];
    float mx = -1e30f;
#pragma unroll
    for (int i = 0; i < 12; ++i) { w12[i] = s_aw[g][h * 12 + i]; mx = fmaxf(mx, w12[i]); }
    float sum = 0.f;
#pragma unroll
    for (int i = 0; i < 12; ++i) { w12[i] = __expf(w12[i] - mx); sum += w12[i]; }
    const float inv = 1.f / sum;

    const int   Ls[3]   = {100, 50, 25};
    const int   st[3]   = {0, 10000, 12500};
    const float invN[3] = {0.01f, 0.02f, 0.04f};

    float4 acc = make_float4(0.f, 0.f, 0.f, 0.f);
    const float* vb = v + (size_t)b * LTOT * EMBED + h * HD + c4;

#pragma unroll
    for (int nl = 0; nl < 3; ++nl) {
        const int   Wl = Ls[nl], Hl = Ls[nl];
        const float fS = (float)Wl;
        const int   base = st[nl];
#pragma unroll
        for (int p2 = 0; p2 < 8; ++p2) {
            const int p  = p2 & 3;
            const int rs = (p2 >> 2) & 1;                 // right-side select
            const int ob = ((h * 3 + nl) * 4 + p) * 4 + rs * 2;
            const float ox = s_off[g][ob], oy = s_off[g][ob + 1];
            const float rx = s_ref[g][nl][rs * 2], ry = s_ref[g][nl][rs * 2 + 1];
            const float x = (rx + ox * invN[nl]) * fS - 0.5f;
            const float y = (ry + oy * invN[nl]) * fS - 0.5f;
            const float x0 = floorf(x), y0 = floorf(y);
            const float tx = x - x0,   ty = y - y0;
            const int ix = (int)x0, iy = (int)y0;
            const float aww = w12[nl * 4 + p] * inv;

            // clamped indices + masked weights (uniform control flow)
            const int x0c = min(max(ix, 0), Wl - 1);
            const int x1c = min(max(ix + 1, 0), Wl - 1);
            const int y0c = min(max(iy, 0), Hl - 1);
            const int y1c = min(max(iy + 1, 0), Hl - 1);
            const float vx0 = (ix     >= 0 && ix     < Wl) ? 1.f : 0.f;
            const float vx1 = (ix + 1 >= 0 && ix + 1 < Wl) ? 1.f : 0.f;
            const float vy0 = (iy     >= 0 && iy     < Hl) ? 1.f : 0.f;
            const float vy1 = (iy + 1 >= 0 && iy + 1 < Hl) ? 1.f : 0.f;

            const float w00 = (1.f - tx) * (1.f - ty) * vx0 * vy0 * aww;
            const float w10 = tx         * (1.f - ty) * vx1 * vy0 * aww;
            const float w01 = (1.f - tx) * ty         * vx0 * vy1 * aww;
            const float w11 = tx         * ty         * vx1 * vy1 * aww;

            const float4 g00 = *reinterpret_cast<const float4*>(vb + (size_t)(base + y0c * Wl + x0c) * EMBED);
            const float4 g10 = *reinterpret_cast<const float4*>(vb + (size_t)(base + y0c * Wl + x1c) * EMBED);
            const float4 g01 = *reinterpret_cast<const float4*>(vb + (size_t)(base + y1c * Wl + x0c) * EMBED);
            const float4 g11 = *reinterpret_cast<const float4*>(vb + (size_t)(base + y1c * Wl + x1c) * EMBED);

            acc.x = fmaf(w00, g00.x, fmaf(w10, g10.x, fmaf(w01, g01.x, fmaf(w11, g11.x, acc.x))));
            acc.y = fmaf(w00, g00.y, fmaf(w10, g10.y, fmaf(w01, g01.y, fmaf(w11, g11.y, acc.y))));
            acc.z = fmaf(w00, g00.z, fmaf(w10, g10.z, fmaf(w01, g01.z, fmaf(w11, g11.z, acc.z))));
            acc.w = fmaf(w00, g00.w, fmaf(w10, g10.w, fmaf(w01, g01.w, fmaf(w11, g11.w, acc.w))));
        }
    }
    *reinterpret_cast<float4*>(out_pre + (size_t)bq * EMBED + h * HD + c4) = acc;
}

// ---------------------------------------------------------------------------
extern "C" void kernel_launch(void* const* d_in, const int* in_sizes, int n_in,
                              void* d_out, int out_size, void* d_ws, size_t ws_size,
                              hipStream_t stream)
{
    const float* query  = (const float*)d_in[0];
    const float* refl   = (const float*)d_in[1];
    const float* refr   = (const float*)d_in[2];
    const float* value  = (const float*)d_in[3];
    // d_in[4]: value_spatial_shapes (static, hardcoded)
    const unsigned char* vmask = (const unsigned char*)d_in[5];
    const float* W_off  = (const float*)d_in[6];
    const float* b_off  = (const float*)d_in[7];
    const float* W_attn = (const float*)d_in[8];
    const float* b_attn = (const float*)d_in[9];
    const float* W_val  = (const float*)d_in[10];
    const float* b_val  = (const float*)d_in[11];
    const float* W_out  = (const float*)d_in[12];
    const float* b_out  = (const float*)d_in[13];

    const int MV = BQ * LTOT;   // 52500 value rows
    const int MQ = BQ * LQ;     // 20400 query rows

    float* ws   = (float*)d_ws;
    float* v    = ws;                          // [MV][256]
    float* offb = v    + (size_t)MV * 256;     // [MQ][384]
    float* awb  = offb + (size_t)MQ * 384;     // [MQ][96]
    float* outp = awb  + (size_t)MQ * 96;      // [MQ][256]

    // 1) value projection (+mask)  : [52500,512] x [256,512]^T
    gemm_bt<<<dim3(2, (MV + 127) / 128), 256, 0, stream>>>(
        value, W_val, b_val, v, MV, 256, 512, vmask);

    // 2) offsets                   : [20400,256] x [384,256]^T
    gemm_bt<<<dim3(3, (MQ + 127) / 128), 256, 0, stream>>>(
        query, W_off, b_off, offb, MQ, 384, 256, nullptr);

    // 3) attention logits          : [20400,256] x [96,256]^T
    gemm_bt<<<dim3(1, (MQ + 127) / 128), 256, 0, stream>>>(
        query, W_attn, b_attn, awb, MQ, 96, 256, nullptr);

    // 4) fused softmax + sampling (4 queries per block)
    msda_sample<<<dim3(MQ / 4), 256, 0, stream>>>(v, offb, awb, refl, refr, outp);

    // 5) output projection         : [20400,256] x [256,256]^T
    gemm_bt<<<dim3(2, (MQ + 127) / 128), 256, 0, stream>>>(
        outp, W_out, b_out, (float*)d_out, MQ, 256, 256, nullptr);
}

// Round 4
// 520.084 us; speedup vs baseline: 1.2049x; 1.2049x over previous
//
#include <hip/hip_runtime.h>

#define NH    8
#define NLVL  3
#define NP    4
#define HD    32
#define EMBED 256

constexpr int LTOT = 13125;   // 100*100 + 50*50 + 25*25
constexpr int BQ   = 4;
constexpr int NQ   = 300;
constexpr int NK   = 17;
constexpr int LQ   = NQ * NK; // 5100

typedef short bf16x8 __attribute__((ext_vector_type(8)));
typedef float f32x4  __attribute__((ext_vector_type(4)));

__device__ __forceinline__ unsigned short bf16_rne(float x) {
    unsigned u = __float_as_uint(x);
    unsigned r = u + 0x7FFFu + ((u >> 16) & 1u);
    return (unsigned short)(r >> 16);
}

// split x into hi (bf16 RNE) and lo (bf16 of residual): x ~= hi + lo, err ~2^-17|x|
__device__ __forceinline__ void split8(const float* __restrict__ p, bool valid,
                                       bf16x8& h, bf16x8& l) {
    float x[8];
    if (valid) {
        float4 a = *reinterpret_cast<const float4*>(p);
        float4 b = *reinterpret_cast<const float4*>(p + 4);
        x[0]=a.x; x[1]=a.y; x[2]=a.z; x[3]=a.w;
        x[4]=b.x; x[5]=b.y; x[6]=b.z; x[7]=b.w;
    } else {
#pragma unroll
        for (int e = 0; e < 8; ++e) x[e] = 0.f;
    }
#pragma unroll
    for (int e = 0; e < 8; ++e) {
        unsigned short hs = bf16_rne(x[e]);
        h[e] = (short)hs;
        float fh = __uint_as_float(((unsigned)hs) << 16);
        l[e] = (short)bf16_rne(x[e] - fh);
    }
}

// ---------------------------------------------------------------------------
// C[M,N] = A[M,K] @ W[N,K]^T + bias, optional row zero-mask.
// bf16x3 split-precision MFMA (hi*hi + lo*hi + hi*lo), fp32 accumulate.
// 128x128 tile, BK=32, 256 thr = 4 waves (2x2), each wave 64x64 = 4x4 frags
// of mfma_f32_16x16x32_bf16. LDS is fragment-contiguous: cell i of a
// 16-row block maps to lane i -> ds_read_b128/ds_write_b128 fully linear.
// Requires K % 32 == 0.
// ---------------------------------------------------------------------------
__global__ __launch_bounds__(256)
void gemm_bt_mfma(const float* __restrict__ A, const float* __restrict__ W,
                  const float* __restrict__ bias, float* __restrict__ C,
                  int M, int N, int K, const unsigned char* __restrict__ rowmask)
{
    __shared__ short Ah[4096], Al[4096], Bh[4096], Bl[4096];  // 4 x 8 KB

    const int tid  = threadIdx.x;
    const int lane = tid & 63;
    const int w    = tid >> 6;
    const int wr   = w >> 1, wc = w & 1;
    const int row0 = blockIdx.y * 128;
    const int col0 = blockIdx.x * 128;

    f32x4 acc[4][4];
#pragma unroll
    for (int i = 0; i < 4; ++i)
#pragma unroll
        for (int j = 0; j < 4; ++j) acc[i][j] = (f32x4)(0.f);

    for (int k0 = 0; k0 < K; k0 += 32) {
        // ---- stage: each thread fills cells tid and tid+256 of A and B ----
#pragma unroll
        for (int s = 0; s < 2; ++s) {
            const int i  = tid + s * 256;        // cell 0..511
            const int rb = i >> 6;               // 16-row block 0..7
            const int kb = (i >> 4) & 3;         // k-group 0..3 (8 wide)
            const int m  = i & 15;               // row within block
            const int r  = rb * 16 + m;          // tile row 0..127
            const int kk = k0 + kb * 8;

            bf16x8 h, l;
            const int ga = row0 + r;
            split8(A + (size_t)ga * K + kk, ga < M, h, l);
            ((bf16x8*)Ah)[i] = h;  ((bf16x8*)Al)[i] = l;

            const int gb = col0 + r;
            split8(W + (size_t)gb * K + kk, gb < N, h, l);
            ((bf16x8*)Bh)[i] = h;  ((bf16x8*)Bl)[i] = l;
        }
        __syncthreads();

        // ---- fragments: lane l of frag rb reads cell rb*64 + l (linear) ----
        bf16x8 ah[4], al[4], bh[4], bl[4];
#pragma unroll
        for (int ii = 0; ii < 4; ++ii) {
            ah[ii] = ((bf16x8*)Ah)[(wr * 4 + ii) * 64 + lane];
            al[ii] = ((bf16x8*)Al)[(wr * 4 + ii) * 64 + lane];
            bh[ii] = ((bf16x8*)Bh)[(wc * 4 + ii) * 64 + lane];
            bl[ii] = ((bf16x8*)Bl)[(wc * 4 + ii) * 64 + lane];
        }

#pragma unroll
        for (int ii = 0; ii < 4; ++ii)
#pragma unroll
            for (int jj = 0; jj < 4; ++jj) {
                acc[ii][jj] = __builtin_amdgcn_mfma_f32_16x16x32_bf16(
                    ah[ii], bh[jj], acc[ii][jj], 0, 0, 0);
                acc[ii][jj] = __builtin_amdgcn_mfma_f32_16x16x32_bf16(
                    al[ii], bh[jj], acc[ii][jj], 0, 0, 0);
                acc[ii][jj] = __builtin_amdgcn_mfma_f32_16x16x32_bf16(
                    ah[ii], bl[jj], acc[ii][jj], 0, 0, 0);
            }
        __syncthreads();
    }

    // ---- epilogue: C/D layout col=lane&15, row=(lane>>4)*4+reg ----
    const int rbase = row0 + wr * 64 + (lane >> 4) * 4;
    const int cbase = col0 + wc * 64 + (lane & 15);
#pragma unroll
    for (int jj = 0; jj < 4; ++jj) {
        const int col = cbase + jj * 16;
        if (col >= N) continue;
        const float bv = bias ? bias[col] : 0.f;
#pragma unroll
        for (int ii = 0; ii < 4; ++ii) {
#pragma unroll
            for (int r4 = 0; r4 < 4; ++r4) {
                const int row = rbase + ii * 16 + r4;
                if (row >= M) continue;
                const float keep = (rowmask && rowmask[row]) ? 0.f : 1.f;
                C[(size_t)row * N + col] = (acc[ii][jj][r4] + bv) * keep;
            }
        }
    }
}

// ---------------------------------------------------------------------------
// Fused softmax + bilinear sampling + head-weighted accumulation.
// 256 threads = 4 groups of 64; each group handles one (b,lq).
// Thread in group: head h = t>>3, channel quad c4 = (t&7)*4 -> float4 math.
// Branch-free border handling: clamp indices, zero the corner weight.
// ---------------------------------------------------------------------------
__global__ __launch_bounds__(256)
void msda_sample(const float* __restrict__ v,     // [B][L][256]
                 const float* __restrict__ off,   // [B*LQ][384]
                 const float* __restrict__ aw,    // [B*LQ][96]
                 const float* __restrict__ refl,  // [B][NQ][NL][NK][2]
                 const float* __restrict__ refr,
                 float* __restrict__ out_pre)     // [B*LQ][256]
{
    const int g   = threadIdx.x >> 6;     // group 0..3
    const int t   = threadIdx.x & 63;     // lane in group
    const int bq  = blockIdx.x * 4 + g;
    const int b   = bq / LQ;
    const int lqi = bq - b * LQ;
    const int iq  = lqi / NK;
    const int ik  = lqi - iq * NK;

    __shared__ float s_off[4][384];
    __shared__ float s_aw[4][96];
    __shared__ float s_ref[4][NLVL][4];   // lx, ly, rx, ry

    {
        const float* offp = off + (size_t)bq * 384;
        for (int i = t; i < 384; i += 64) s_off[g][i] = offp[i];
        const float* awp = aw + (size_t)bq * 96;
        for (int i = t; i < 96; i += 64) s_aw[g][i] = awp[i];
        if (t < 12) {
            const int nl = t >> 2, comp = t & 3;
            const float* rp = (comp < 2) ? refl : refr;
            s_ref[g][nl][comp] =
                rp[((((size_t)b * NQ + iq) * NLVL + nl) * NK + ik) * 2 + (comp & 1)];
        }
    }
    __syncthreads();

    const int h  = t >> 3;          // 0..7
    const int c4 = (t & 7) * 4;     // 0,4,...,28

    // softmax over the 12 (nl, p) logits of this head
    float w12[12];
    float mx = -1e30f;
#pragma unroll
    for (int i = 0; i < 12; ++i) { w12[i] = s_aw[g][h * 12 + i]; mx = fmaxf(mx, w12[i]); }
    float sum = 0.f;
#pragma unroll
    for (int i = 0; i < 12; ++i) { w12[i] = __expf(w12[i] - mx); sum += w12[i]; }
    const float inv = 1.f / sum;

    const int   Ls[3]   = {100, 50, 25};
    const int   st[3]   = {0, 10000, 12500};
    const float invN[3] = {0.01f, 0.02f, 0.04f};

    float4 acc = make_float4(0.f, 0.f, 0.f, 0.f);
    const float* vb = v + (size_t)b * LTOT * EMBED + h * HD + c4;

#pragma unroll
    for (int nl = 0; nl < 3; ++nl) {
        const int   Wl = Ls[nl], Hl = Ls[nl];
        const float fS = (float)Wl;
        const int   base = st[nl];
#pragma unroll
        for (int p2 = 0; p2 < 8; ++p2) {
            const int p  = p2 & 3;
            const int rs = (p2 >> 2) & 1;                 // right-side select
            const int ob = ((h * 3 + nl) * 4 + p) * 4 + rs * 2;
            const float ox = s_off[g][ob], oy = s_off[g][ob + 1];
            const float rx = s_ref[g][nl][rs * 2], ry = s_ref[g][nl][rs * 2 + 1];
            const float x = (rx + ox * invN[nl]) * fS - 0.5f;
            const float y = (ry + oy * invN[nl]) * fS - 0.5f;
            const float x0 = floorf(x), y0 = floorf(y);
            const float tx = x - x0,   ty = y - y0;
            const int ix = (int)x0, iy = (int)y0;
            const float aww = w12[nl * 4 + p] * inv;

            // clamped indices + masked weights (uniform control flow)
            const int x0c = min(max(ix, 0), Wl - 1);
            const int x1c = min(max(ix + 1, 0), Wl - 1);
            const int y0c = min(max(iy, 0), Hl - 1);
            const int y1c = min(max(iy + 1, 0), Hl - 1);
            const float vx0 = (ix     >= 0 && ix     < Wl) ? 1.f : 0.f;
            const float vx1 = (ix + 1 >= 0 && ix + 1 < Wl) ? 1.f : 0.f;
            const float vy0 = (iy     >= 0 && iy     < Hl) ? 1.f : 0.f;
            const float vy1 = (iy + 1 >= 0 && iy + 1 < Hl) ? 1.f : 0.f;

            const float w00 = (1.f - tx) * (1.f - ty) * vx0 * vy0 * aww;
            const float w10 = tx         * (1.f - ty) * vx1 * vy0 * aww;
            const float w01 = (1.f - tx) * ty         * vx0 * vy1 * aww;
            const float w11 = tx         * ty         * vx1 * vy1 * aww;

            const float4 g00 = *reinterpret_cast<const float4*>(vb + (size_t)(base + y0c * Wl + x0c) * EMBED);
            const float4 g10 = *reinterpret_cast<const float4*>(vb + (size_t)(base + y0c * Wl + x1c) * EMBED);
            const float4 g01 = *reinterpret_cast<const float4*>(vb + (size_t)(base + y1c * Wl + x0c) * EMBED);
            const float4 g11 = *reinterpret_cast<const float4*>(vb + (size_t)(base + y1c * Wl + x1c) * EMBED);

            acc.x = fmaf(w00, g00.x, fmaf(w10, g10.x, fmaf(w01, g01.x, fmaf(w11, g11.x, acc.x))));
            acc.y = fmaf(w00, g00.y, fmaf(w10, g10.y, fmaf(w01, g01.y, fmaf(w11, g11.y, acc.y))));
            acc.z = fmaf(w00, g00.z, fmaf(w10, g10.z, fmaf(w01, g01.z, fmaf(w11, g11.z, acc.z))));
            acc.w = fmaf(w00, g00.w, fmaf(w10, g10.w, fmaf(w01, g01.w, fmaf(w11, g11.w, acc.w))));
        }
    }
    *reinterpret_cast<float4*>(out_pre + (size_t)bq * EMBED + h * HD + c4) = acc;
}

// ---------------------------------------------------------------------------
extern "C" void kernel_launch(void* const* d_in, const int* in_sizes, int n_in,
                              void* d_out, int out_size, void* d_ws, size_t ws_size,
                              hipStream_t stream)
{
    const float* query  = (const float*)d_in[0];
    const float* refl   = (const float*)d_in[1];
    const float* refr   = (const float*)d_in[2];
    const float* value  = (const float*)d_in[3];
    // d_in[4]: value_spatial_shapes (static, hardcoded)
    const unsigned char* vmask = (const unsigned char*)d_in[5];
    const float* W_off  = (const float*)d_in[6];
    const float* b_off  = (const float*)d_in[7];
    const float* W_attn = (const float*)d_in[8];
    const float* b_attn = (const float*)d_in[9];
    const float* W_val  = (const float*)d_in[10];
    const float* b_val  = (const float*)d_in[11];
    const float* W_out  = (const float*)d_in[12];
    const float* b_out  = (const float*)d_in[13];

    const int MV = BQ * LTOT;   // 52500 value rows
    const int MQ = BQ * LQ;     // 20400 query rows

    float* ws   = (float*)d_ws;
    float* v    = ws;                          // [MV][256]
    float* offb = v    + (size_t)MV * 256;     // [MQ][384]
    float* awb  = offb + (size_t)MQ * 384;     // [MQ][96]
    float* outp = awb  + (size_t)MQ * 96;      // [MQ][256]

    // 1) value projection (+mask)  : [52500,512] x [256,512]^T
    gemm_bt_mfma<<<dim3(2, (MV + 127) / 128), 256, 0, stream>>>(
        value, W_val, b_val, v, MV, 256, 512, vmask);

    // 2) offsets                   : [20400,256] x [384,256]^T
    gemm_bt_mfma<<<dim3(3, (MQ + 127) / 128), 256, 0, stream>>>(
        query, W_off, b_off, offb, MQ, 384, 256, nullptr);

    // 3) attention logits          : [20400,256] x [96,256]^T
    gemm_bt_mfma<<<dim3(1, (MQ + 127) / 128), 256, 0, stream>>>(
        query, W_attn, b_attn, awb, MQ, 96, 256, nullptr);

    // 4) fused softmax + sampling (4 queries per block)
    msda_sample<<<dim3(MQ / 4), 256, 0, stream>>>(v, offb, awb, refl, refr, outp);

    // 5) output projection         : [20400,256] x [256,256]^T
    gemm_bt_mfma<<<dim3(2, (MQ + 127) / 128), 256, 0, stream>>>(
        outp, W_out, b_out, (float*)d_out, MQ, 256, 256, nullptr);
}

// Round 5
// 418.960 us; speedup vs baseline: 1.4957x; 1.2414x over previous
//
#include <hip/hip_runtime.h>
#include <hip/hip_fp16.h>

#define NH    8
#define NLVL  3
#define HD    32
#define EMBED 256

constexpr int LTOT = 13125;   // 100*100 + 50*50 + 25*25
constexpr int BQ   = 4;
constexpr int NQ   = 300;
constexpr int NK   = 17;
constexpr int LQ   = NQ * NK;     // 5100
constexpr int MV   = BQ * LTOT;   // 52500
constexpr int MQ   = BQ * LQ;     // 20400

typedef short bf16x8 __attribute__((ext_vector_type(8)));
typedef float f32x4  __attribute__((ext_vector_type(4)));

__device__ __forceinline__ unsigned short bf16_rne(float x) {
    unsigned u = __float_as_uint(x);
    unsigned r = u + 0x7FFFu + ((u >> 16) & 1u);
    return (unsigned short)(r >> 16);
}

// x ~= hi + lo with bf16 hi, lo; combined error ~2^-17 |x|
__device__ __forceinline__ void split8v(const float4 a, const float4 b,
                                        bf16x8& h, bf16x8& l) {
    float x[8] = {a.x, a.y, a.z, a.w, b.x, b.y, b.z, b.w};
#pragma unroll
    for (int e = 0; e < 8; ++e) {
        unsigned short hs = bf16_rne(x[e]);
        h[e] = (short)hs;
        float fh = __uint_as_float(((unsigned)hs) << 16);
        l[e] = (short)bf16_rne(x[e] - fh);
    }
}

// ---------------------------------------------------------------------------
// One-pass split of query + all weights into bf16 hi/lo (W_off & W_attn are
// concatenated into Wqc[480][256]); also builds the fused qc bias.
// ---------------------------------------------------------------------------
constexpr int CV_Q    = 1305600;             // query float4s
constexpr int CV_WV   = CV_Q    + 32768;     // + W_val
constexpr int CV_WOFF = CV_WV   + 24576;     // + W_off
constexpr int CV_WAT  = CV_WOFF + 6144;      // + W_attn
constexpr int CV_TOT  = CV_WAT  + 16384;     // + W_out

__global__ __launch_bounds__(256)
void convert_split(const float* __restrict__ query, const float* __restrict__ Wval,
                   const float* __restrict__ Woff, const float* __restrict__ Wattn,
                   const float* __restrict__ Wout,
                   const float* __restrict__ boff, const float* __restrict__ battn,
                   unsigned short* __restrict__ qh,   unsigned short* __restrict__ ql,
                   unsigned short* __restrict__ Wvh,  unsigned short* __restrict__ Wvl,
                   unsigned short* __restrict__ Wqch, unsigned short* __restrict__ Wqcl,
                   unsigned short* __restrict__ Woh,  unsigned short* __restrict__ Wol,
                   float* __restrict__ bqc)
{
    const int idx = blockIdx.x * 256 + threadIdx.x;
    if (idx < 480) bqc[idx] = (idx < 384) ? boff[idx] : battn[idx - 384];
    if (idx >= CV_TOT) return;

    const float* src; unsigned short *dh, *dl; size_t e;
    if      (idx < CV_Q)    { src = query; dh = qh;   dl = ql;   e = (size_t)idx * 4; }
    else if (idx < CV_WV)   { src = Wval;  dh = Wvh;  dl = Wvl;  e = (size_t)(idx - CV_Q) * 4; }
    else if (idx < CV_WOFF) { src = Woff;  dh = Wqch; dl = Wqcl; e = (size_t)(idx - CV_WV) * 4; }
    else if (idx < CV_WAT)  { src = Wattn; dh = Wqch + 98304; dl = Wqcl + 98304; e = (size_t)(idx - CV_WOFF) * 4; }
    else                    { src = Wout;  dh = Woh;  dl = Wol;  e = (size_t)(idx - CV_WAT) * 4; }

    const float4 x = *reinterpret_cast<const float4*>(src + e);
    ushort4 hh, ll;
    hh.x = bf16_rne(x.x); ll.x = bf16_rne(x.x - __uint_as_float((unsigned)hh.x << 16));
    hh.y = bf16_rne(x.y); ll.y = bf16_rne(x.y - __uint_as_float((unsigned)hh.y << 16));
    hh.z = bf16_rne(x.z); ll.z = bf16_rne(x.z - __uint_as_float((unsigned)hh.z << 16));
    hh.w = bf16_rne(x.w); ll.w = bf16_rne(x.w - __uint_as_float((unsigned)hh.w << 16));
    *reinterpret_cast<ushort4*>(dh + e) = hh;
    *reinterpret_cast<ushort4*>(dl + e) = ll;
}

// ---------------------------------------------------------------------------
// C[M,N] = A[M,K] @ W[N,K]^T + bias. bf16x3 split MFMA, fp32 accumulate.
// 128x128 tile, BK=32, 4 waves (2x2). Double-buffered LDS (64 KB), reg-staged:
// issue loads(t+1) -> ds_read+MFMA(t) -> convert/ds_write(t+1) -> barrier.
// AF32: A is fp32, split in-kernel. Else A is pre-split bf16 hi/lo.
// OUTF16: write __half with row zero-mask; else fp32.
// ---------------------------------------------------------------------------
template<bool AF32, bool OUTF16>
__global__ __launch_bounds__(256)
void gemm_mfma(const float* __restrict__ A32,
               const unsigned short* __restrict__ Ahg, const unsigned short* __restrict__ Alg,
               const unsigned short* __restrict__ Bhg, const unsigned short* __restrict__ Blg,
               const float* __restrict__ bias,
               float* __restrict__ Cf, __half* __restrict__ Ch,
               int M, int N, int K, const unsigned char* __restrict__ rowmask)
{
    __shared__ short Ah[2][4096], Al[2][4096], Bh[2][4096], Bl[2][4096];

    const int tid  = threadIdx.x;
    const int lane = tid & 63;
    const int w    = tid >> 6;
    const int wr   = w >> 1, wc = w & 1;
    const int row0 = blockIdx.y * 128;
    const int col0 = blockIdx.x * 128;
    const int nt   = K >> 5;

    // cell coords: i = rb*64 + kb*16 + m -> row rb*16+m, k-offset kb*8
    int cr[2], ck[2];
#pragma unroll
    for (int s = 0; s < 2; ++s) {
        const int i = tid + s * 256;
        cr[s] = ((i >> 6) << 4) + (i & 15);
        ck[s] = ((i >> 4) & 3) << 3;
    }

    float4 a32r[2][2];
    uint4  ahr[2], alr[2], bhr[2], blr[2];

    auto issue = [&](int kt) {
        const int kk = kt << 5;
#pragma unroll
        for (int s = 0; s < 2; ++s) {
            const int ga = row0 + cr[s];
            const size_t ao = (size_t)ga * K + kk + ck[s];
            if constexpr (AF32) {
                if (ga < M) {
                    a32r[s][0] = *reinterpret_cast<const float4*>(A32 + ao);
                    a32r[s][1] = *reinterpret_cast<const float4*>(A32 + ao + 4);
                } else {
                    a32r[s][0] = make_float4(0.f, 0.f, 0.f, 0.f);
                    a32r[s][1] = make_float4(0.f, 0.f, 0.f, 0.f);
                }
            } else {
                if (ga < M) {
                    ahr[s] = *reinterpret_cast<const uint4*>(Ahg + ao);
                    alr[s] = *reinterpret_cast<const uint4*>(Alg + ao);
                } else {
                    ahr[s] = make_uint4(0, 0, 0, 0);
                    alr[s] = make_uint4(0, 0, 0, 0);
                }
            }
            const int gb = col0 + cr[s];
            const size_t bo = (size_t)gb * K + kk + ck[s];
            if (gb < N) {
                bhr[s] = *reinterpret_cast<const uint4*>(Bhg + bo);
                blr[s] = *reinterpret_cast<const uint4*>(Blg + bo);
            } else {
                bhr[s] = make_uint4(0, 0, 0, 0);
                blr[s] = make_uint4(0, 0, 0, 0);
            }
        }
    };
    auto commit = [&](int buf) {
#pragma unroll
        for (int s = 0; s < 2; ++s) {
            const int i = tid + s * 256;
            if constexpr (AF32) {
                bf16x8 h, l;
                split8v(a32r[s][0], a32r[s][1], h, l);
                ((bf16x8*)Ah[buf])[i] = h;
                ((bf16x8*)Al[buf])[i] = l;
            } else {
                *reinterpret_cast<uint4*>(&Ah[buf][i * 8]) = ahr[s];
                *reinterpret_cast<uint4*>(&Al[buf][i * 8]) = alr[s];
            }
            *reinterpret_cast<uint4*>(&Bh[buf][i * 8]) = bhr[s];
            *reinterpret_cast<uint4*>(&Bl[buf][i * 8]) = blr[s];
        }
    };

    f32x4 acc[4][4];
#pragma unroll
    for (int i = 0; i < 4; ++i)
#pragma unroll
        for (int j = 0; j < 4; ++j) acc[i][j] = (f32x4)(0.f);

    issue(0);
    commit(0);
    __syncthreads();

    int cur = 0;
    for (int t = 0; t < nt; ++t) {
        const bool more = (t + 1 < nt);
        if (more) issue(t + 1);

        bf16x8 af[4], alf[4], bhf[4], blf[4];
#pragma unroll
        for (int ii = 0; ii < 4; ++ii) {
            af[ii]  = ((bf16x8*)Ah[cur])[(wr * 4 + ii) * 64 + lane];
            alf[ii] = ((bf16x8*)Al[cur])[(wr * 4 + ii) * 64 + lane];
            bhf[ii] = ((bf16x8*)Bh[cur])[(wc * 4 + ii) * 64 + lane];
            blf[ii] = ((bf16x8*)Bl[cur])[(wc * 4 + ii) * 64 + lane];
        }
#pragma unroll
        for (int ii = 0; ii < 4; ++ii)
#pragma unroll
            for (int jj = 0; jj < 4; ++jj) {
                acc[ii][jj] = __builtin_amdgcn_mfma_f32_16x16x32_bf16(af[ii],  bhf[jj], acc[ii][jj], 0, 0, 0);
                acc[ii][jj] = __builtin_amdgcn_mfma_f32_16x16x32_bf16(alf[ii], bhf[jj], acc[ii][jj], 0, 0, 0);
                acc[ii][jj] = __builtin_amdgcn_mfma_f32_16x16x32_bf16(af[ii],  blf[jj], acc[ii][jj], 0, 0, 0);
            }
        if (more) {
            commit(cur ^ 1);
            __syncthreads();
        }
        cur ^= 1;
    }

    // epilogue: C/D layout col=lane&15, row=(lane>>4)*4+reg
    const int rbase = row0 + wr * 64 + (lane >> 4) * 4;
    const int cbase = col0 + wc * 64 + (lane & 15);
#pragma unroll
    for (int jj = 0; jj < 4; ++jj) {
        const int col = cbase + jj * 16;
        if (col >= N) continue;
        const float bv = bias[col];
#pragma unroll
        for (int ii = 0; ii < 4; ++ii)
#pragma unroll
            for (int r4 = 0; r4 < 4; ++r4) {
                const int row = rbase + ii * 16 + r4;
                if (row >= M) continue;
                float val = acc[ii][jj][r4] + bv;
                if constexpr (OUTF16) {
                    if (rowmask[row]) val = 0.f;
                    Ch[(size_t)row * N + col] = __float2half(val);
                } else {
                    Cf[(size_t)row * N + col] = val;
                }
            }
    }
}

// ---------------------------------------------------------------------------
// Fused softmax + bilinear sampling + head-weighted accumulation.
// 256 threads = 4 groups of 64; group = one (b,lq); thread = (head, 4 channels).
// v is fp16; output written pre-split as bf16 hi/lo for the out-proj GEMM.
// ---------------------------------------------------------------------------
__global__ __launch_bounds__(256)
void msda_sample(const __half* __restrict__ v,    // [B][L][256] fp16
                 const float* __restrict__ qo,    // [B*LQ][480] = off(384)|aw(96)
                 const float* __restrict__ refl,  // [B][NQ][NL][NK][2]
                 const float* __restrict__ refr,
                 unsigned short* __restrict__ oph, // [B*LQ][256] bf16 hi
                 unsigned short* __restrict__ opl) // [B*LQ][256] bf16 lo
{
    const int g   = threadIdx.x >> 6;
    const int t   = threadIdx.x & 63;
    const int bq  = blockIdx.x * 4 + g;
    const int b   = bq / LQ;
    const int lqi = bq - b * LQ;
    const int iq  = lqi / NK;
    const int ik  = lqi - iq * NK;

    __shared__ float s_off[4][384];
    __shared__ float s_aw[4][96];
    __shared__ float s_ref[4][NLVL][4];   // lx, ly, rx, ry

    {
        const float* qop = qo + (size_t)bq * 480;
        for (int i = t; i < 384; i += 64) s_off[g][i] = qop[i];
        for (int i = t; i < 96;  i += 64) s_aw[g][i]  = qop[384 + i];
        if (t < 12) {
            const int nl = t >> 2, comp = t & 3;
            const float* rp = (comp < 2) ? refl : refr;
            s_ref[g][nl][comp] =
                rp[((((size_t)b * NQ + iq) * NLVL + nl) * NK + ik) * 2 + (comp & 1)];
        }
    }
    __syncthreads();

    const int h  = t >> 3;
    const int c4 = (t & 7) * 4;

    float w12[12];
    float mx = -1e30f;
#pragma unroll
    for (int i = 0; i < 12; ++i) { w12[i] = s_aw[g][h * 12 + i]; mx = fmaxf(mx, w12[i]); }
    float sum = 0.f;
#pragma unroll
    for (int i = 0; i < 12; ++i) { w12[i] = __expf(w12[i] - mx); sum += w12[i]; }
    const float inv = 1.f / sum;

    const int   Ls[3]   = {100, 50, 25};
    const int   st[3]   = {0, 10000, 12500};
    const float invN[3] = {0.01f, 0.02f, 0.04f};

    float4 acc = make_float4(0.f, 0.f, 0.f, 0.f);
    const __half* vb = v + (size_t)b * LTOT * EMBED + h * HD + c4;

    struct __align__(8) H4 { __half2 a, b; };

#pragma unroll
    for (int nl = 0; nl < 3; ++nl) {
        const int   Wl = Ls[nl], Hl = Ls[nl];
        const float fS = (float)Wl;
        const int   base = st[nl];
#pragma unroll
        for (int p2 = 0; p2 < 8; ++p2) {
            const int p  = p2 & 3;
            const int rs = (p2 >> 2) & 1;
            const int ob = ((h * 3 + nl) * 4 + p) * 4 + rs * 2;
            const float ox = s_off[g][ob], oy = s_off[g][ob + 1];
            const float rx = s_ref[g][nl][rs * 2], ry = s_ref[g][nl][rs * 2 + 1];
            const float x = (rx + ox * invN[nl]) * fS - 0.5f;
            const float y = (ry + oy * invN[nl]) * fS - 0.5f;
            const float x0 = floorf(x), y0 = floorf(y);
            const float tx = x - x0,   ty = y - y0;
            const int ix = (int)x0, iy = (int)y0;
            const float aww = w12[nl * 4 + p] * inv;

            const int x0c = min(max(ix, 0), Wl - 1);
            const int x1c = min(max(ix + 1, 0), Wl - 1);
            const int y0c = min(max(iy, 0), Hl - 1);
            const int y1c = min(max(iy + 1, 0), Hl - 1);
            const float vx0 = (ix     >= 0 && ix     < Wl) ? 1.f : 0.f;
            const float vx1 = (ix + 1 >= 0 && ix + 1 < Wl) ? 1.f : 0.f;
            const float vy0 = (iy     >= 0 && iy     < Hl) ? 1.f : 0.f;
            const float vy1 = (iy + 1 >= 0 && iy + 1 < Hl) ? 1.f : 0.f;

            const float w00 = (1.f - tx) * (1.f - ty) * vx0 * vy0 * aww;
            const float w10 = tx         * (1.f - ty) * vx1 * vy0 * aww;
            const float w01 = (1.f - tx) * ty         * vx0 * vy1 * aww;
            const float w11 = tx         * ty         * vx1 * vy1 * aww;

            const H4 g00 = *reinterpret_cast<const H4*>(vb + (size_t)(base + y0c * Wl + x0c) * EMBED);
            const H4 g10 = *reinterpret_cast<const H4*>(vb + (size_t)(base + y0c * Wl + x1c) * EMBED);
            const H4 g01 = *reinterpret_cast<const H4*>(vb + (size_t)(base + y1c * Wl + x0c) * EMBED);
            const H4 g11 = *reinterpret_cast<const H4*>(vb + (size_t)(base + y1c * Wl + x1c) * EMBED);

            const float2 f00a = __half22float2(g00.a), f00b = __half22float2(g00.b);
            const float2 f10a = __half22float2(g10.a), f10b = __half22float2(g10.b);
            const float2 f01a = __half22float2(g01.a), f01b = __half22float2(g01.b);
            const float2 f11a = __half22float2(g11.a), f11b = __half22float2(g11.b);

            acc.x = fmaf(w00, f00a.x, fmaf(w10, f10a.x, fmaf(w01, f01a.x, fmaf(w11, f11a.x, acc.x))));
            acc.y = fmaf(w00, f00a.y, fmaf(w10, f10a.y, fmaf(w01, f01a.y, fmaf(w11, f11a.y, acc.y))));
            acc.z = fmaf(w00, f00b.x, fmaf(w10, f10b.x, fmaf(w01, f01b.x, fmaf(w11, f11b.x, acc.z))));
            acc.w = fmaf(w00, f00b.y, fmaf(w10, f10b.y, fmaf(w01, f01b.y, fmaf(w11, f11b.y, acc.w))));
        }
    }

    const size_t obase = (size_t)bq * EMBED + h * HD + c4;
    ushort4 hh, ll;
    hh.x = bf16_rne(acc.x); ll.x = bf16_rne(acc.x - __uint_as_float((unsigned)hh.x << 16));
    hh.y = bf16_rne(acc.y); ll.y = bf16_rne(acc.y - __uint_as_float((unsigned)hh.y << 16));
    hh.z = bf16_rne(acc.z); ll.z = bf16_rne(acc.z - __uint_as_float((unsigned)hh.z << 16));
    hh.w = bf16_rne(acc.w); ll.w = bf16_rne(acc.w - __uint_as_float((unsigned)hh.w << 16));
    *reinterpret_cast<ushort4*>(oph + obase) = hh;
    *reinterpret_cast<ushort4*>(opl + obase) = ll;
}

// ---------------------------------------------------------------------------
extern "C" void kernel_launch(void* const* d_in, const int* in_sizes, int n_in,
                              void* d_out, int out_size, void* d_ws, size_t ws_size,
                              hipStream_t stream)
{
    const float* query  = (const float*)d_in[0];
    const float* refl   = (const float*)d_in[1];
    const float* refr   = (const float*)d_in[2];
    const float* value  = (const float*)d_in[3];
    const unsigned char* vmask = (const unsigned char*)d_in[5];
    const float* W_off  = (const float*)d_in[6];
    const float* b_off  = (const float*)d_in[7];
    const float* W_attn = (const float*)d_in[8];
    const float* b_attn = (const float*)d_in[9];
    const float* W_val  = (const float*)d_in[10];
    const float* b_val  = (const float*)d_in[11];
    const float* W_out  = (const float*)d_in[12];
    const float* b_out  = (const float*)d_in[13];

    char* p = (char*)d_ws;
    __half* v            = (__half*)p;          p += (size_t)MV * 256 * 2;   // 26.88 MB
    unsigned short* qh   = (unsigned short*)p;  p += (size_t)MQ * 256 * 2;   // 10.44 MB
    unsigned short* ql   = (unsigned short*)p;  p += (size_t)MQ * 256 * 2;
    float* qo            = (float*)p;           p += (size_t)MQ * 480 * 4;   // 39.17 MB
    unsigned short* oph  = (unsigned short*)p;  p += (size_t)MQ * 256 * 2;
    unsigned short* opl  = (unsigned short*)p;  p += (size_t)MQ * 256 * 2;
    unsigned short* Wvh  = (unsigned short*)p;  p += 131072 * 2;
    unsigned short* Wvl  = (unsigned short*)p;  p += 131072 * 2;
    unsigned short* Wqch = (unsigned short*)p;  p += 122880 * 2;
    unsigned short* Wqcl = (unsigned short*)p;  p += 122880 * 2;
    unsigned short* Woh  = (unsigned short*)p;  p += 65536 * 2;
    unsigned short* Wol  = (unsigned short*)p;  p += 65536 * 2;
    float* bqc           = (float*)p;           p += 480 * 4;

    // 0) split query + weights to bf16 hi/lo (+ fused qc bias)
    convert_split<<<dim3((CV_TOT + 255) / 256), 256, 0, stream>>>(
        query, W_val, W_off, W_attn, W_out, b_off, b_attn,
        qh, ql, Wvh, Wvl, Wqch, Wqcl, Woh, Wol, bqc);

    // 1) value projection (+mask) -> fp16 v : [52500,512] x [256,512]^T
    gemm_mfma<true, true><<<dim3(2, (MV + 127) / 128), 256, 0, stream>>>(
        value, nullptr, nullptr, Wvh, Wvl, b_val, nullptr, v, MV, 256, 512, vmask);

    // 2) fused offsets+attn logits : [20400,256] x [480,256]^T
    gemm_mfma<false, false><<<dim3(4, (MQ + 127) / 128), 256, 0, stream>>>(
        nullptr, qh, ql, Wqch, Wqcl, bqc, qo, nullptr, MQ, 480, 256, nullptr);

    // 3) fused softmax + sampling (4 queries per block), pre-split output
    msda_sample<<<dim3(MQ / 4), 256, 0, stream>>>(v, qo, refl, refr, oph, opl);

    // 4) output projection : [20400,256] x [256,256]^T
    gemm_mfma<false, false><<<dim3(2, (MQ + 127) / 128), 256, 0, stream>>>(
        nullptr, oph, opl, Woh, Wol, b_out, (float*)d_out, nullptr, MQ, 256, 256, nullptr);
}

// Round 6
// 386.478 us; speedup vs baseline: 1.6214x; 1.0840x over previous
//
#include <hip/hip_runtime.h>

#define NH    8
#define NLVL  3
#define HD    32
#define EMBED 256

constexpr int LTOT = 13125;   // 100*100 + 50*50 + 25*25
constexpr int BQ   = 4;
constexpr int NQ   = 300;
constexpr int NK   = 17;
constexpr int LQ   = NQ * NK;     // 5100
constexpr int MV   = BQ * LTOT;   // 52500
constexpr int MQ   = BQ * LQ;     // 20400

typedef _Float16 f16x8 __attribute__((ext_vector_type(8)));
typedef _Float16 f16x4 __attribute__((ext_vector_type(4)));
typedef float    f32x4 __attribute__((ext_vector_type(4)));

// ---------------------------------------------------------------------------
// Weights -> fp16 (W_off & W_attn concatenated to Wqc[480][256]) + fused bias.
// ---------------------------------------------------------------------------
constexpr int CW_WV   = 32768;               // W_val float4s
constexpr int CW_WOFF = CW_WV   + 24576;     // + W_off
constexpr int CW_WAT  = CW_WOFF + 6144;      // + W_attn
constexpr int CW_TOT  = CW_WAT  + 16384;     // + W_out

__global__ __launch_bounds__(256)
void convert_w(const float* __restrict__ Wval, const float* __restrict__ Woff,
               const float* __restrict__ Wattn, const float* __restrict__ Wout,
               const float* __restrict__ boff, const float* __restrict__ battn,
               _Float16* __restrict__ Wv16, _Float16* __restrict__ Wqc16,
               _Float16* __restrict__ Wo16, float* __restrict__ bqc)
{
    const int idx = blockIdx.x * 256 + threadIdx.x;
    if (idx < 480) bqc[idx] = (idx < 384) ? boff[idx] : battn[idx - 384];
    if (idx >= CW_TOT) return;

    const float* src; _Float16* dst; size_t e;
    if      (idx < CW_WV)   { src = Wval;  dst = Wv16;          e = (size_t)idx * 4; }
    else if (idx < CW_WOFF) { src = Woff;  dst = Wqc16;         e = (size_t)(idx - CW_WV) * 4; }
    else if (idx < CW_WAT)  { src = Wattn; dst = Wqc16 + 98304; e = (size_t)(idx - CW_WOFF) * 4; }
    else                    { src = Wout;  dst = Wo16;          e = (size_t)(idx - CW_WAT) * 4; }

    const float4 x = *reinterpret_cast<const float4*>(src + e);
    f16x4 o;
    o[0] = (_Float16)x.x; o[1] = (_Float16)x.y;
    o[2] = (_Float16)x.z; o[3] = (_Float16)x.w;
    *reinterpret_cast<f16x4*>(dst + e) = o;
}

// ---------------------------------------------------------------------------
// C[M,N] = A[M,K] @ W[N,K]^T + bias.  A fp32 split in-kernel to fp16 hi+lo,
// B pre-converted fp16 -> 2 MFMA passes (hi*B + lo*B), fp32 accumulate.
// 128x128 tile, BK=32, 4 waves (2x2). Double-buffered LDS (48 KB), reg-staged.
// OUT==0: fp32 row-major.  OUT==1: fp16 head-major [B][NH][LTOT][32] + mask.
// ---------------------------------------------------------------------------
template<int OUT>
__global__ __launch_bounds__(256)
void gemm_f16(const float* __restrict__ A,
              const _Float16* __restrict__ Bg,
              const float* __restrict__ bias,
              float* __restrict__ Cf, _Float16* __restrict__ Ch,
              int M, int N, int K, const unsigned char* __restrict__ rowmask)
{
    __shared__ _Float16 Ah[2][4096], Al[2][4096], Bh[2][4096];

    const int tid  = threadIdx.x;
    const int lane = tid & 63;
    const int w    = tid >> 6;
    const int wr   = w >> 1, wc = w & 1;
    const int row0 = blockIdx.y * 128;
    const int col0 = blockIdx.x * 128;
    const int nt   = K >> 5;

    // cell i = rb*64 + kb*16 + m  ->  tile row rb*16+m, k-offset kb*8
    int cr[2], ck[2];
#pragma unroll
    for (int s = 0; s < 2; ++s) {
        const int i = tid + s * 256;
        cr[s] = ((i >> 6) << 4) + (i & 15);
        ck[s] = ((i >> 4) & 3) << 3;
    }

    float4 a32r[2][2];
    uint4  bhr[2];

    auto issue = [&](int kt) {
        const int kk = kt << 5;
#pragma unroll
        for (int s = 0; s < 2; ++s) {
            const int ga = row0 + cr[s];
            if (ga < M) {
                const float* ap = A + (size_t)ga * K + kk + ck[s];
                a32r[s][0] = *reinterpret_cast<const float4*>(ap);
                a32r[s][1] = *reinterpret_cast<const float4*>(ap + 4);
            } else {
                a32r[s][0] = make_float4(0.f, 0.f, 0.f, 0.f);
                a32r[s][1] = make_float4(0.f, 0.f, 0.f, 0.f);
            }
            const int gb = col0 + cr[s];
            if (gb < N)
                bhr[s] = *reinterpret_cast<const uint4*>(Bg + (size_t)gb * K + kk + ck[s]);
            else
                bhr[s] = make_uint4(0, 0, 0, 0);
        }
    };
    auto commit = [&](int buf) {
#pragma unroll
        for (int s = 0; s < 2; ++s) {
            const int i = tid + s * 256;
            float x[8] = {a32r[s][0].x, a32r[s][0].y, a32r[s][0].z, a32r[s][0].w,
                          a32r[s][1].x, a32r[s][1].y, a32r[s][1].z, a32r[s][1].w};
            f16x8 h, l;
#pragma unroll
            for (int e = 0; e < 8; ++e) {
                _Float16 hh = (_Float16)x[e];
                h[e] = hh;
                l[e] = (_Float16)(x[e] - (float)hh);
            }
            ((f16x8*)Ah[buf])[i] = h;
            ((f16x8*)Al[buf])[i] = l;
            *reinterpret_cast<uint4*>(&Bh[buf][i * 8]) = bhr[s];
        }
    };

    f32x4 acc[4][4];
#pragma unroll
    for (int i = 0; i < 4; ++i)
#pragma unroll
        for (int j = 0; j < 4; ++j) acc[i][j] = (f32x4)(0.f);

    issue(0);
    commit(0);
    __syncthreads();

    int cur = 0;
    for (int t = 0; t < nt; ++t) {
        const bool more = (t + 1 < nt);
        if (more) issue(t + 1);

        f16x8 af[4], alf[4], bf[4];
#pragma unroll
        for (int ii = 0; ii < 4; ++ii) {
            af[ii]  = ((f16x8*)Ah[cur])[(wr * 4 + ii) * 64 + lane];
            alf[ii] = ((f16x8*)Al[cur])[(wr * 4 + ii) * 64 + lane];
            bf[ii]  = ((f16x8*)Bh[cur])[(wc * 4 + ii) * 64 + lane];
        }
#pragma unroll
        for (int ii = 0; ii < 4; ++ii)
#pragma unroll
            for (int jj = 0; jj < 4; ++jj) {
                acc[ii][jj] = __builtin_amdgcn_mfma_f32_16x16x32_f16(af[ii],  bf[jj], acc[ii][jj], 0, 0, 0);
                acc[ii][jj] = __builtin_amdgcn_mfma_f32_16x16x32_f16(alf[ii], bf[jj], acc[ii][jj], 0, 0, 0);
            }
        if (more) {
            commit(cur ^ 1);
            __syncthreads();
        }
        cur ^= 1;
    }

    // epilogue: C/D layout col=lane&15, row=(lane>>4)*4+reg
    const int rbase = row0 + wr * 64 + (lane >> 4) * 4;
    const int cbase = col0 + wc * 64 + (lane & 15);
#pragma unroll
    for (int jj = 0; jj < 4; ++jj) {
        const int col = cbase + jj * 16;
        if (col >= N) continue;
        const float bv = bias[col];
#pragma unroll
        for (int ii = 0; ii < 4; ++ii)
#pragma unroll
            for (int r4 = 0; r4 < 4; ++r4) {
                const int row = rbase + ii * 16 + r4;
                if (row >= M) continue;
                float val = acc[ii][jj][r4] + bv;
                if constexpr (OUT == 1) {
                    if (rowmask[row]) val = 0.f;
                    const unsigned br = (unsigned)row / 13125u;   // batch
                    const int      lr = row - (int)br * 13125;    // spatial idx
                    const int      hh = col >> 5, ch = col & 31;
                    Ch[(((size_t)br * NH + hh) * LTOT + lr) * 32 + ch] = (_Float16)val;
                } else {
                    Cf[(size_t)row * N + col] = val;
                }
            }
    }
}

// ---------------------------------------------------------------------------
// Fused softmax + bilinear sampling + head-weighted accumulation.
// 256 threads = 4 groups of 64; group = one (b,lq); thread = (head, 4 chans).
// v is fp16 head-major [B][NH][LTOT][32] -> corner pairs are adjacent 64 B.
// ---------------------------------------------------------------------------
__global__ __launch_bounds__(256)
void msda_sample(const _Float16* __restrict__ v,
                 const float* __restrict__ qo,    // [B*LQ][480] = off|aw
                 const float* __restrict__ refl,  // [B][NQ][NL][NK][2]
                 const float* __restrict__ refr,
                 float* __restrict__ out_pre)     // [B*LQ][256]
{
    const int g   = threadIdx.x >> 6;
    const int t   = threadIdx.x & 63;
    const int bq  = blockIdx.x * 4 + g;
    const int b   = bq / LQ;
    const int lqi = bq - b * LQ;
    const int iq  = lqi / NK;
    const int ik  = lqi - iq * NK;

    __shared__ float s_off[4][384];
    __shared__ float s_aw[4][96];
    __shared__ float s_ref[4][NLVL][4];   // lx, ly, rx, ry

    {
        const float* qop = qo + (size_t)bq * 480;
        for (int i = t; i < 384; i += 64) s_off[g][i] = qop[i];
        for (int i = t; i < 96;  i += 64) s_aw[g][i]  = qop[384 + i];
        if (t < 12) {
            const int nl = t >> 2, comp = t & 3;
            const float* rp = (comp < 2) ? refl : refr;
            s_ref[g][nl][comp] =
                rp[((((size_t)b * NQ + iq) * NLVL + nl) * NK + ik) * 2 + (comp & 1)];
        }
    }
    __syncthreads();

    const int h  = t >> 3;
    const int c4 = (t & 7) * 4;

    float w12[12];
    float mx = -1e30f;
#pragma unroll
    for (int i = 0; i < 12; ++i) { w12[i] = s_aw[g][h * 12 + i]; mx = fmaxf(mx, w12[i]); }
    float sum = 0.f;
#pragma unroll
    for (int i = 0; i < 12; ++i) { w12[i] = __expf(w12[i] - mx); sum += w12[i]; }
    const float inv = 1.f / sum;

    const int   Ls[3]   = {100, 50, 25};
    const int   st[3]   = {0, 10000, 12500};
    const float invN[3] = {0.01f, 0.02f, 0.04f};

    float4 acc = make_float4(0.f, 0.f, 0.f, 0.f);
    const _Float16* vb = v + ((size_t)(b * NH + h) * LTOT) * 32 + c4;

#pragma unroll
    for (int nl = 0; nl < 3; ++nl) {
        const int   Wl = Ls[nl], Hl = Ls[nl];
        const float fS = (float)Wl;
        const int   base = st[nl];
#pragma unroll
        for (int p2 = 0; p2 < 8; ++p2) {
            const int p  = p2 & 3;
            const int rs = (p2 >> 2) & 1;
            const int ob = ((h * 3 + nl) * 4 + p) * 4 + rs * 2;
            const float ox = s_off[g][ob], oy = s_off[g][ob + 1];
            const float rx = s_ref[g][nl][rs * 2], ry = s_ref[g][nl][rs * 2 + 1];
            const float x = (rx + ox * invN[nl]) * fS - 0.5f;
            const float y = (ry + oy * invN[nl]) * fS - 0.5f;
            const float x0 = floorf(x), y0 = floorf(y);
            const float tx = x - x0,   ty = y - y0;
            const int ix = (int)x0, iy = (int)y0;
            const float aww = w12[nl * 4 + p] * inv;

            const int x0c = min(max(ix, 0), Wl - 1);
            const int x1c = min(max(ix + 1, 0), Wl - 1);
            const int y0c = min(max(iy, 0), Hl - 1);
            const int y1c = min(max(iy + 1, 0), Hl - 1);
            const float vx0 = (ix     >= 0 && ix     < Wl) ? 1.f : 0.f;
            const float vx1 = (ix + 1 >= 0 && ix + 1 < Wl) ? 1.f : 0.f;
            const float vy0 = (iy     >= 0 && iy     < Hl) ? 1.f : 0.f;
            const float vy1 = (iy + 1 >= 0 && iy + 1 < Hl) ? 1.f : 0.f;

            const float w00 = (1.f - tx) * (1.f - ty) * vx0 * vy0 * aww;
            const float w10 = tx         * (1.f - ty) * vx1 * vy0 * aww;
            const float w01 = (1.f - tx) * ty         * vx0 * vy1 * aww;
            const float w11 = tx         * ty         * vx1 * vy1 * aww;

            const f16x4 g00 = *reinterpret_cast<const f16x4*>(vb + (size_t)(base + y0c * Wl + x0c) * 32);
            const f16x4 g10 = *reinterpret_cast<const f16x4*>(vb + (size_t)(base + y0c * Wl + x1c) * 32);
            const f16x4 g01 = *reinterpret_cast<const f16x4*>(vb + (size_t)(base + y1c * Wl + x0c) * 32);
            const f16x4 g11 = *reinterpret_cast<const f16x4*>(vb + (size_t)(base + y1c * Wl + x1c) * 32);

            acc.x = fmaf(w00, (float)g00[0], fmaf(w10, (float)g10[0], fmaf(w01, (float)g01[0], fmaf(w11, (float)g11[0], acc.x))));
            acc.y = fmaf(w00, (float)g00[1], fmaf(w10, (float)g10[1], fmaf(w01, (float)g01[1], fmaf(w11, (float)g11[1], acc.y))));
            acc.z = fmaf(w00, (float)g00[2], fmaf(w10, (float)g10[2], fmaf(w01, (float)g01[2], fmaf(w11, (float)g11[2], acc.z))));
            acc.w = fmaf(w00, (float)g00[3], fmaf(w10, (float)g10[3], fmaf(w01, (float)g01[3], fmaf(w11, (float)g11[3], acc.w))));
        }
    }
    *reinterpret_cast<float4*>(out_pre + (size_t)bq * EMBED + h * HD + c4) = acc;
}

// ---------------------------------------------------------------------------
extern "C" void kernel_launch(void* const* d_in, const int* in_sizes, int n_in,
                              void* d_out, int out_size, void* d_ws, size_t ws_size,
                              hipStream_t stream)
{
    const float* query  = (const float*)d_in[0];
    const float* refl   = (const float*)d_in[1];
    const float* refr   = (const float*)d_in[2];
    const float* value  = (const float*)d_in[3];
    const unsigned char* vmask = (const unsigned char*)d_in[5];
    const float* W_off  = (const float*)d_in[6];
    const float* b_off  = (const float*)d_in[7];
    const float* W_attn = (const float*)d_in[8];
    const float* b_attn = (const float*)d_in[9];
    const float* W_val  = (const float*)d_in[10];
    const float* b_val  = (const float*)d_in[11];
    const float* W_out  = (const float*)d_in[12];
    const float* b_out  = (const float*)d_in[13];

    char* p = (char*)d_ws;
    _Float16* v      = (_Float16*)p;  p += (size_t)MV * 256 * 2;   // 26.88 MB, head-major
    float* qo        = (float*)p;     p += (size_t)MQ * 480 * 4;   // 39.17 MB
    float* outp      = (float*)p;     p += (size_t)MQ * 256 * 4;   // 20.89 MB
    _Float16* Wv16   = (_Float16*)p;  p += 131072 * 2;
    _Float16* Wqc16  = (_Float16*)p;  p += 122880 * 2;
    _Float16* Wo16   = (_Float16*)p;  p += 65536 * 2;
    float* bqc       = (float*)p;     p += 480 * 4;

    // 0) weights -> fp16 (+ fused qc bias)
    convert_w<<<dim3((CW_TOT + 255) / 256), 256, 0, stream>>>(
        W_val, W_off, W_attn, W_out, b_off, b_attn, Wv16, Wqc16, Wo16, bqc);

    // 1) value projection (+mask) -> fp16 head-major v : [52500,512]x[256,512]^T
    gemm_f16<1><<<dim3(2, (MV + 127) / 128), 256, 0, stream>>>(
        value, Wv16, b_val, nullptr, v, MV, 256, 512, vmask);

    // 2) fused offsets+attn logits : [20400,256] x [480,256]^T
    gemm_f16<0><<<dim3(4, (MQ + 127) / 128), 256, 0, stream>>>(
        query, Wqc16, bqc, qo, nullptr, MQ, 480, 256, nullptr);

    // 3) fused softmax + sampling (4 queries per block)
    msda_sample<<<dim3(MQ / 4), 256, 0, stream>>>(v, qo, refl, refr, outp);

    // 4) output projection : [20400,256] x [256,256]^T
    gemm_f16<0><<<dim3(2, (MQ + 127) / 128), 256, 0, stream>>>(
        outp, Wo16, b_out, (float*)d_out, nullptr, MQ, 256, 256, nullptr);
}

// Round 7
// 383.024 us; speedup vs baseline: 1.6360x; 1.0090x over previous
//
#include <hip/hip_runtime.h>

#define NH    8
#define NLVL  3
#define HD    32
#define EMBED 256

constexpr int LTOT = 13125;   // 100*100 + 50*50 + 25*25
constexpr int BQ   = 4;
constexpr int NQ   = 300;
constexpr int NK   = 17;
constexpr int LQ   = NQ * NK;     // 5100
constexpr int MV   = BQ * LTOT;   // 52500
constexpr int MQ   = BQ * LQ;     // 20400

typedef _Float16 f16x8 __attribute__((ext_vector_type(8)));
typedef _Float16 f16x4 __attribute__((ext_vector_type(4)));
typedef float    f32x4 __attribute__((ext_vector_type(4)));

// ---------------------------------------------------------------------------
// Weights -> fp16 (W_off & W_attn concatenated to Wqc[480][256]) + fused bias.
// ---------------------------------------------------------------------------
constexpr int CW_WV   = 32768;               // W_val float4s
constexpr int CW_WOFF = CW_WV   + 24576;     // + W_off
constexpr int CW_WAT  = CW_WOFF + 6144;      // + W_attn
constexpr int CW_TOT  = CW_WAT  + 16384;     // + W_out

__global__ __launch_bounds__(256)
void convert_w(const float* __restrict__ Wval, const float* __restrict__ Woff,
               const float* __restrict__ Wattn, const float* __restrict__ Wout,
               const float* __restrict__ boff, const float* __restrict__ battn,
               _Float16* __restrict__ Wv16, _Float16* __restrict__ Wqc16,
               _Float16* __restrict__ Wo16, float* __restrict__ bqc)
{
    const int idx = blockIdx.x * 256 + threadIdx.x;
    if (idx < 480) bqc[idx] = (idx < 384) ? boff[idx] : battn[idx - 384];
    if (idx >= CW_TOT) return;

    const float* src; _Float16* dst; size_t e;
    if      (idx < CW_WV)   { src = Wval;  dst = Wv16;          e = (size_t)idx * 4; }
    else if (idx < CW_WOFF) { src = Woff;  dst = Wqc16;         e = (size_t)(idx - CW_WV) * 4; }
    else if (idx < CW_WAT)  { src = Wattn; dst = Wqc16 + 98304; e = (size_t)(idx - CW_WOFF) * 4; }
    else                    { src = Wout;  dst = Wo16;          e = (size_t)(idx - CW_WAT) * 4; }

    const float4 x = *reinterpret_cast<const float4*>(src + e);
    f16x4 o;
    o[0] = (_Float16)x.x; o[1] = (_Float16)x.y;
    o[2] = (_Float16)x.z; o[3] = (_Float16)x.w;
    *reinterpret_cast<f16x4*>(dst + e) = o;
}

// ---------------------------------------------------------------------------
// C[M,N] = A[M,K] @ W[N,K]^T + bias.  fp16 MFMA, fp32 accumulate.
// AF16: A already fp16 (direct 16B loads); else fp32, converted in-kernel.
// OUT: 0 = fp32 row-major, 1 = fp16 head-major [B][NH][LTOT][32] (+row mask),
//      2 = fp16 row-major.
// 128x128 tile, BK=32, 4 waves (2x2). Double-buffered LDS (32 KB), reg-staged:
// issue loads(t+1) -> ds_read+MFMA(t) -> commit(t+1) -> barrier.
// ---------------------------------------------------------------------------
template<bool AF16, int OUT>
__global__ __launch_bounds__(256)
void gemm_f16(const float* __restrict__ A32, const _Float16* __restrict__ A16,
              const _Float16* __restrict__ Bg,
              const float* __restrict__ bias,
              float* __restrict__ Cf, _Float16* __restrict__ Ch,
              int M, int N, int K, const unsigned char* __restrict__ rowmask)
{
    __shared__ _Float16 Ah[2][4096], Bh[2][4096];   // 2 x (8+8) KB

    const int tid  = threadIdx.x;
    const int lane = tid & 63;
    const int w    = tid >> 6;
    const int wr   = w >> 1, wc = w & 1;
    const int row0 = blockIdx.y * 128;
    const int col0 = blockIdx.x * 128;
    const int nt   = K >> 5;

    // cell i = rb*64 + kb*16 + m  ->  tile row rb*16+m, k-offset kb*8
    int cr[2], ck[2];
#pragma unroll
    for (int s = 0; s < 2; ++s) {
        const int i = tid + s * 256;
        cr[s] = ((i >> 6) << 4) + (i & 15);
        ck[s] = ((i >> 4) & 3) << 3;
    }

    float4 a32r[2][2];
    uint4  a16r[2], bhr[2];

    auto issue = [&](int kt) {
        const int kk = kt << 5;
#pragma unroll
        for (int s = 0; s < 2; ++s) {
            const int ga = row0 + cr[s];
            const size_t ao = (size_t)ga * K + kk + ck[s];
            if constexpr (AF16) {
                if (ga < M) a16r[s] = *reinterpret_cast<const uint4*>(A16 + ao);
                else        a16r[s] = make_uint4(0, 0, 0, 0);
            } else {
                if (ga < M) {
                    a32r[s][0] = *reinterpret_cast<const float4*>(A32 + ao);
                    a32r[s][1] = *reinterpret_cast<const float4*>(A32 + ao + 4);
                } else {
                    a32r[s][0] = make_float4(0.f, 0.f, 0.f, 0.f);
                    a32r[s][1] = make_float4(0.f, 0.f, 0.f, 0.f);
                }
            }
            const int gb = col0 + cr[s];
            if (gb < N)
                bhr[s] = *reinterpret_cast<const uint4*>(Bg + (size_t)gb * K + kk + ck[s]);
            else
                bhr[s] = make_uint4(0, 0, 0, 0);
        }
    };
    auto commit = [&](int buf) {
#pragma unroll
        for (int s = 0; s < 2; ++s) {
            const int i = tid + s * 256;
            if constexpr (AF16) {
                *reinterpret_cast<uint4*>(&Ah[buf][i * 8]) = a16r[s];
            } else {
                float x[8] = {a32r[s][0].x, a32r[s][0].y, a32r[s][0].z, a32r[s][0].w,
                              a32r[s][1].x, a32r[s][1].y, a32r[s][1].z, a32r[s][1].w};
                f16x8 h;
#pragma unroll
                for (int e = 0; e < 8; ++e) h[e] = (_Float16)x[e];
                ((f16x8*)Ah[buf])[i] = h;
            }
            *reinterpret_cast<uint4*>(&Bh[buf][i * 8]) = bhr[s];
        }
    };

    f32x4 acc[4][4];
#pragma unroll
    for (int i = 0; i < 4; ++i)
#pragma unroll
        for (int j = 0; j < 4; ++j) acc[i][j] = (f32x4)(0.f);

    issue(0);
    commit(0);
    __syncthreads();

    int cur = 0;
    for (int t = 0; t < nt; ++t) {
        const bool more = (t + 1 < nt);
        if (more) issue(t + 1);

        f16x8 af[4], bf[4];
#pragma unroll
        for (int ii = 0; ii < 4; ++ii) {
            af[ii] = ((f16x8*)Ah[cur])[(wr * 4 + ii) * 64 + lane];
            bf[ii] = ((f16x8*)Bh[cur])[(wc * 4 + ii) * 64 + lane];
        }
#pragma unroll
        for (int ii = 0; ii < 4; ++ii)
#pragma unroll
            for (int jj = 0; jj < 4; ++jj)
                acc[ii][jj] = __builtin_amdgcn_mfma_f32_16x16x32_f16(af[ii], bf[jj], acc[ii][jj], 0, 0, 0);

        if (more) {
            commit(cur ^ 1);
            __syncthreads();
        }
        cur ^= 1;
    }

    // epilogue: C/D layout col=lane&15, row=(lane>>4)*4+reg
    const int rbase = row0 + wr * 64 + (lane >> 4) * 4;
    const int cbase = col0 + wc * 64 + (lane & 15);
#pragma unroll
    for (int jj = 0; jj < 4; ++jj) {
        const int col = cbase + jj * 16;
        if (col >= N) continue;
        const float bv = bias[col];
#pragma unroll
        for (int ii = 0; ii < 4; ++ii)
#pragma unroll
            for (int r4 = 0; r4 < 4; ++r4) {
                const int row = rbase + ii * 16 + r4;
                if (row >= M) continue;
                float val = acc[ii][jj][r4] + bv;
                if constexpr (OUT == 1) {
                    if (rowmask[row]) val = 0.f;
                    const unsigned br = (unsigned)row / 13125u;   // batch
                    const int      lr = row - (int)br * 13125;    // spatial idx
                    const int      hh = col >> 5, ch = col & 31;
                    Ch[(((size_t)br * NH + hh) * LTOT + lr) * 32 + ch] = (_Float16)val;
                } else if constexpr (OUT == 2) {
                    Ch[(size_t)row * N + col] = (_Float16)val;
                } else {
                    Cf[(size_t)row * N + col] = val;
                }
            }
    }
}

// ---------------------------------------------------------------------------
// Fused softmax + bilinear sampling + head-weighted accumulation.
// 256 threads = 4 groups of 64; group = one (b,lq); thread = (head, 4 chans).
// v fp16 head-major [B][NH][LTOT][32]; qo fp16; output fp16 row-major.
// ---------------------------------------------------------------------------
__global__ __launch_bounds__(256)
void msda_sample(const _Float16* __restrict__ v,
                 const _Float16* __restrict__ qo,  // [B*LQ][480] = off|aw
                 const float* __restrict__ refl,   // [B][NQ][NL][NK][2]
                 const float* __restrict__ refr,
                 _Float16* __restrict__ out_pre)   // [B*LQ][256] fp16
{
    const int g   = threadIdx.x >> 6;
    const int t   = threadIdx.x & 63;
    const int bq  = blockIdx.x * 4 + g;
    const int b   = bq / LQ;
    const int lqi = bq - b * LQ;
    const int iq  = lqi / NK;
    const int ik  = lqi - iq * NK;

    __shared__ float s_off[4][384];
    __shared__ float s_aw[4][96];
    __shared__ float s_ref[4][NLVL][4];   // lx, ly, rx, ry

    {
        const _Float16* qop = qo + (size_t)bq * 480;
        for (int i = t; i < 384; i += 64) s_off[g][i] = (float)qop[i];
        for (int i = t; i < 96;  i += 64) s_aw[g][i]  = (float)qop[384 + i];
        if (t < 12) {
            const int nl = t >> 2, comp = t & 3;
            const float* rp = (comp < 2) ? refl : refr;
            s_ref[g][nl][comp] =
                rp[((((size_t)b * NQ + iq) * NLVL + nl) * NK + ik) * 2 + (comp & 1)];
        }
    }
    __syncthreads();

    const int h  = t >> 3;
    const int c4 = (t & 7) * 4;

    float w12[12];
    float mx = -1e30f;
#pragma unroll
    for (int i = 0; i < 12; ++i) { w12[i] = s_aw[g][h * 12 + i]; mx = fmaxf(mx, w12[i]); }
    float sum = 0.f;
#pragma unroll
    for (int i = 0; i < 12; ++i) { w12[i] = __expf(w12[i] - mx); sum += w12[i]; }
    const float inv = 1.f / sum;

    const int   Ls[3]   = {100, 50, 25};
    const int   st[3]   = {0, 10000, 12500};
    const float invN[3] = {0.01f, 0.02f, 0.04f};

    float4 acc = make_float4(0.f, 0.f, 0.f, 0.f);
    const _Float16* vb = v + ((size_t)(b * NH + h) * LTOT) * 32 + c4;

#pragma unroll
    for (int nl = 0; nl < 3; ++nl) {
        const int   Wl = Ls[nl], Hl = Ls[nl];
        const float fS = (float)Wl;
        const int   base = st[nl];
#pragma unroll
        for (int p2 = 0; p2 < 8; ++p2) {
            const int p  = p2 & 3;
            const int rs = (p2 >> 2) & 1;
            const int ob = ((h * 3 + nl) * 4 + p) * 4 + rs * 2;
            const float ox = s_off[g][ob], oy = s_off[g][ob + 1];
            const float rx = s_ref[g][nl][rs * 2], ry = s_ref[g][nl][rs * 2 + 1];
            const float x = (rx + ox * invN[nl]) * fS - 0.5f;
            const float y = (ry + oy * invN[nl]) * fS - 0.5f;
            const float x0 = floorf(x), y0 = floorf(y);
            const float tx = x - x0,   ty = y - y0;
            const int ix = (int)x0, iy = (int)y0;
            const float aww = w12[nl * 4 + p] * inv;

            const int x0c = min(max(ix, 0), Wl - 1);
            const int x1c = min(max(ix + 1, 0), Wl - 1);
            const int y0c = min(max(iy, 0), Hl - 1);
            const int y1c = min(max(iy + 1, 0), Hl - 1);
            const float vx0 = (ix     >= 0 && ix     < Wl) ? 1.f : 0.f;
            const float vx1 = (ix + 1 >= 0 && ix + 1 < Wl) ? 1.f : 0.f;
            const float vy0 = (iy     >= 0 && iy     < Hl) ? 1.f : 0.f;
            const float vy1 = (iy + 1 >= 0 && iy + 1 < Hl) ? 1.f : 0.f;

            const float w00 = (1.f - tx) * (1.f - ty) * vx0 * vy0 * aww;
            const float w10 = tx         * (1.f - ty) * vx1 * vy0 * aww;
            const float w01 = (1.f - tx) * ty         * vx0 * vy1 * aww;
            const float w11 = tx         * ty         * vx1 * vy1 * aww;

            const f16x4 g00 = *reinterpret_cast<const f16x4*>(vb + (size_t)(base + y0c * Wl + x0c) * 32);
            const f16x4 g10 = *reinterpret_cast<const f16x4*>(vb + (size_t)(base + y0c * Wl + x1c) * 32);
            const f16x4 g01 = *reinterpret_cast<const f16x4*>(vb + (size_t)(base + y1c * Wl + x0c) * 32);
            const f16x4 g11 = *reinterpret_cast<const f16x4*>(vb + (size_t)(base + y1c * Wl + x1c) * 32);

            acc.x = fmaf(w00, (float)g00[0], fmaf(w10, (float)g10[0], fmaf(w01, (float)g01[0], fmaf(w11, (float)g11[0], acc.x))));
            acc.y = fmaf(w00, (float)g00[1], fmaf(w10, (float)g10[1], fmaf(w01, (float)g01[1], fmaf(w11, (float)g11[1], acc.y))));
            acc.z = fmaf(w00, (float)g00[2], fmaf(w10, (float)g10[2], fmaf(w01, (float)g01[2], fmaf(w11, (float)g11[2], acc.z))));
            acc.w = fmaf(w00, (float)g00[3], fmaf(w10, (float)g10[3], fmaf(w01, (float)g01[3], fmaf(w11, (float)g11[3], acc.w))));
        }
    }

    f16x4 o;
    o[0] = (_Float16)acc.x; o[1] = (_Float16)acc.y;
    o[2] = (_Float16)acc.z; o[3] = (_Float16)acc.w;
    *reinterpret_cast<f16x4*>(out_pre + (size_t)bq * EMBED + h * HD + c4) = o;
}

// ---------------------------------------------------------------------------
extern "C" void kernel_launch(void* const* d_in, const int* in_sizes, int n_in,
                              void* d_out, int out_size, void* d_ws, size_t ws_size,
                              hipStream_t stream)
{
    const float* query  = (const float*)d_in[0];
    const float* refl   = (const float*)d_in[1];
    const float* refr   = (const float*)d_in[2];
    const float* value  = (const float*)d_in[3];
    const unsigned char* vmask = (const unsigned char*)d_in[5];
    const float* W_off  = (const float*)d_in[6];
    const float* b_off  = (const float*)d_in[7];
    const float* W_attn = (const float*)d_in[8];
    const float* b_attn = (const float*)d_in[9];
    const float* W_val  = (const float*)d_in[10];
    const float* b_val  = (const float*)d_in[11];
    const float* W_out  = (const float*)d_in[12];
    const float* b_out  = (const float*)d_in[13];

    char* p = (char*)d_ws;
    _Float16* v      = (_Float16*)p;  p += (size_t)MV * 256 * 2;   // 26.88 MB head-major
    _Float16* qo     = (_Float16*)p;  p += (size_t)MQ * 480 * 2;   // 19.58 MB
    _Float16* outp   = (_Float16*)p;  p += (size_t)MQ * 256 * 2;   // 10.44 MB
    _Float16* Wv16   = (_Float16*)p;  p += 131072 * 2;
    _Float16* Wqc16  = (_Float16*)p;  p += 122880 * 2;
    _Float16* Wo16   = (_Float16*)p;  p += 65536 * 2;
    float* bqc       = (float*)p;     p += 480 * 4;

    // 0) weights -> fp16 (+ fused qc bias)
    convert_w<<<dim3((CW_TOT + 255) / 256), 256, 0, stream>>>(
        W_val, W_off, W_attn, W_out, b_off, b_attn, Wv16, Wqc16, Wo16, bqc);

    // 1) value projection (+mask) -> fp16 head-major v : [52500,512]x[256,512]^T
    gemm_f16<false, 1><<<dim3(2, (MV + 127) / 128), 256, 0, stream>>>(
        value, nullptr, Wv16, b_val, nullptr, v, MV, 256, 512, vmask);

    // 2) fused offsets+attn logits -> fp16 : [20400,256] x [480,256]^T
    gemm_f16<false, 2><<<dim3(4, (MQ + 127) / 128), 256, 0, stream>>>(
        query, nullptr, Wqc16, bqc, nullptr, qo, MQ, 480, 256, nullptr);

    // 3) fused softmax + sampling (4 queries per block) -> fp16
    msda_sample<<<dim3(MQ / 4), 256, 0, stream>>>(v, qo, refl, refr, outp);

    // 4) output projection : [20400,256] x [256,256]^T (A fp16 direct)
    gemm_f16<true, 0><<<dim3(2, (MQ + 127) / 128), 256, 0, stream>>>(
        nullptr, outp, Wo16, b_out, (float*)d_out, nullptr, MQ, 256, 256, nullptr);
}

// Round 8
// 344.349 us; speedup vs baseline: 1.8198x; 1.1123x over previous
//
#include <hip/hip_runtime.h>

#define NH    8
#define NLVL  3
#define HD    32
#define EMBED 256

constexpr int LTOT = 13125;   // 100*100 + 50*50 + 25*25
constexpr int BQ   = 4;
constexpr int NQ   = 300;
constexpr int NK   = 17;
constexpr int LQ   = NQ * NK;     // 5100
constexpr int MV   = BQ * LTOT;   // 52500
constexpr int MQ   = BQ * LQ;     // 20400

constexpr int NBLK_V  = 822;      // 2 cols x 411 rows
constexpr int NBLK_QC = 640;      // 4 cols x 160 rows
constexpr int QBPB    = 1275;     // sampler blocks per batch (5100/4)

typedef _Float16 f16x8 __attribute__((ext_vector_type(8)));
typedef _Float16 f16x4 __attribute__((ext_vector_type(4)));
typedef float    f32x4 __attribute__((ext_vector_type(4)));

// ---------------------------------------------------------------------------
// Weights -> fp16 (W_off & W_attn concatenated to Wqc[480][256]) + fused bias.
// ---------------------------------------------------------------------------
constexpr int CW_WV   = 32768;               // W_val float4s
constexpr int CW_WOFF = CW_WV   + 24576;     // + W_off
constexpr int CW_WAT  = CW_WOFF + 6144;      // + W_attn
constexpr int CW_TOT  = CW_WAT  + 16384;     // + W_out

__global__ __launch_bounds__(256)
void convert_w(const float* __restrict__ Wval, const float* __restrict__ Woff,
               const float* __restrict__ Wattn, const float* __restrict__ Wout,
               const float* __restrict__ boff, const float* __restrict__ battn,
               _Float16* __restrict__ Wv16, _Float16* __restrict__ Wqc16,
               _Float16* __restrict__ Wo16, float* __restrict__ bqc)
{
    const int idx = blockIdx.x * 256 + threadIdx.x;
    if (idx < 480) bqc[idx] = (idx < 384) ? boff[idx] : battn[idx - 384];
    if (idx >= CW_TOT) return;

    const float* src; _Float16* dst; size_t e;
    if      (idx < CW_WV)   { src = Wval;  dst = Wv16;          e = (size_t)idx * 4; }
    else if (idx < CW_WOFF) { src = Woff;  dst = Wqc16;         e = (size_t)(idx - CW_WV) * 4; }
    else if (idx < CW_WAT)  { src = Wattn; dst = Wqc16 + 98304; e = (size_t)(idx - CW_WOFF) * 4; }
    else                    { src = Wout;  dst = Wo16;          e = (size_t)(idx - CW_WAT) * 4; }

    const float4 x = *reinterpret_cast<const float4*>(src + e);
    f16x4 o;
    o[0] = (_Float16)x.x; o[1] = (_Float16)x.y;
    o[2] = (_Float16)x.z; o[3] = (_Float16)x.w;
    *reinterpret_cast<f16x4*>(dst + e) = o;
}

// ---------------------------------------------------------------------------
// Fused value-proj + qc-proj GEMM. 128x128 tile, BK=32, 512 thr = 8 waves
// (4x2), per-wave 32x64 (acc 2x4). Double-buffered LDS (32 KB), reg-staged.
// blocks [0, 822): value [52500,512]x[256,512]^T -> fp16 head-major + mask
// blocks [822, 1462): qc  [20400,256]x[480,256]^T -> fp16 row-major
// ---------------------------------------------------------------------------
__global__ __launch_bounds__(512)
void gemm_vq(const float* __restrict__ value, const _Float16* __restrict__ Wv,
             const float* __restrict__ bval, _Float16* __restrict__ vout,
             const unsigned char* __restrict__ vmask,
             const float* __restrict__ query, const _Float16* __restrict__ Wqc,
             const float* __restrict__ bqcv, _Float16* __restrict__ qo)
{
    __shared__ _Float16 Ah[2][4096], Bh[2][4096];   // 32 KB

    const int tid  = threadIdx.x;
    const int lane = tid & 63;
    const int w    = tid >> 6;
    const int wr   = w >> 1, wc = w & 1;

    const int  bid = blockIdx.x;
    const bool isV = bid < NBLK_V;
    const float* A; const _Float16* Bg; const float* bias;
    int M, N, K, row0, col0;
    if (isV) {
        A = value; Bg = Wv; bias = bval;
        M = MV; N = 256; K = 512;
        col0 = (bid & 1) << 7; row0 = (bid >> 1) << 7;
    } else {
        const int b2 = bid - NBLK_V;
        A = query; Bg = Wqc; bias = bqcv;
        M = MQ; N = 480; K = 256;
        col0 = (b2 & 3) << 7; row0 = (b2 >> 2) << 7;
    }
    const int nt = K >> 5;

    // cell i = tid: rb = i>>6 (16-row block), kb = (i>>4)&3 (8-wide k), m = i&15
    const int cr = ((tid >> 6) << 4) + (tid & 15);
    const int ck = ((tid >> 4) & 3) << 3;

    float4 a0, a1; uint4 brg;

    auto issue = [&](int kt) {
        const int kk = kt << 5;
        const int ga = row0 + cr;
        if (ga < M) {
            const float* ap = A + (size_t)ga * K + kk + ck;
            a0 = *reinterpret_cast<const float4*>(ap);
            a1 = *reinterpret_cast<const float4*>(ap + 4);
        } else {
            a0 = make_float4(0.f, 0.f, 0.f, 0.f);
            a1 = make_float4(0.f, 0.f, 0.f, 0.f);
        }
        const int gb = col0 + cr;
        if (gb < N)
            brg = *reinterpret_cast<const uint4*>(Bg + (size_t)gb * K + kk + ck);
        else
            brg = make_uint4(0, 0, 0, 0);
    };
    auto commit = [&](int buf) {
        f16x8 h;
        h[0] = (_Float16)a0.x; h[1] = (_Float16)a0.y;
        h[2] = (_Float16)a0.z; h[3] = (_Float16)a0.w;
        h[4] = (_Float16)a1.x; h[5] = (_Float16)a1.y;
        h[6] = (_Float16)a1.z; h[7] = (_Float16)a1.w;
        ((f16x8*)Ah[buf])[tid] = h;
        *reinterpret_cast<uint4*>(&Bh[buf][tid * 8]) = brg;
    };

    f32x4 acc[2][4];
#pragma unroll
    for (int i = 0; i < 2; ++i)
#pragma unroll
        for (int j = 0; j < 4; ++j) acc[i][j] = (f32x4)(0.f);

    issue(0);
    commit(0);
    __syncthreads();

    int cur = 0;
    for (int t = 0; t < nt; ++t) {
        const bool more = (t + 1 < nt);
        if (more) issue(t + 1);

        f16x8 af[2], bf[4];
#pragma unroll
        for (int ii = 0; ii < 2; ++ii)
            af[ii] = ((f16x8*)Ah[cur])[(wr * 2 + ii) * 64 + lane];
#pragma unroll
        for (int jj = 0; jj < 4; ++jj)
            bf[jj] = ((f16x8*)Bh[cur])[(wc * 4 + jj) * 64 + lane];

#pragma unroll
        for (int ii = 0; ii < 2; ++ii)
#pragma unroll
            for (int jj = 0; jj < 4; ++jj)
                acc[ii][jj] = __builtin_amdgcn_mfma_f32_16x16x32_f16(af[ii], bf[jj], acc[ii][jj], 0, 0, 0);

        if (more) {
            commit(cur ^ 1);
            __syncthreads();
        }
        cur ^= 1;
    }

    // epilogue: C/D layout col=lane&15, row=(lane>>4)*4+reg
    const int rbase = row0 + wr * 32 + (lane >> 4) * 4;
    const int cbase = col0 + wc * 64 + (lane & 15);
#pragma unroll
    for (int jj = 0; jj < 4; ++jj) {
        const int col = cbase + jj * 16;
        if (col >= N) continue;
        const float bv = bias[col];
#pragma unroll
        for (int ii = 0; ii < 2; ++ii)
#pragma unroll
            for (int r4 = 0; r4 < 4; ++r4) {
                const int row = rbase + ii * 16 + r4;
                if (row >= M) continue;
                float val = acc[ii][jj][r4] + bv;
                if (isV) {
                    if (vmask[row]) val = 0.f;
                    const unsigned br = (unsigned)row / 13125u;
                    const int      lr = row - (int)br * 13125;
                    const int      hh = col >> 5, ch = col & 31;
                    vout[(((size_t)br * NH + hh) * LTOT + lr) * 32 + ch] = (_Float16)val;
                } else {
                    qo[(size_t)row * 480 + col] = (_Float16)val;
                }
            }
    }
}

// ---------------------------------------------------------------------------
// Output projection: [20400,256] x [256,256]^T + bias -> fp32.
// A fp16 direct. Same 8-wave structure.
// ---------------------------------------------------------------------------
__global__ __launch_bounds__(512)
void gemm_out(const _Float16* __restrict__ A, const _Float16* __restrict__ Bg,
              const float* __restrict__ bias, float* __restrict__ C)
{
    __shared__ _Float16 Ah[2][4096], Bh[2][4096];

    const int tid  = threadIdx.x;
    const int lane = tid & 63;
    const int w    = tid >> 6;
    const int wr   = w >> 1, wc = w & 1;
    const int bid  = blockIdx.x;
    const int col0 = (bid & 1) << 7;
    const int row0 = (bid >> 1) << 7;
    constexpr int M = MQ, N = 256, K = 256, nt = K >> 5;

    const int cr = ((tid >> 6) << 4) + (tid & 15);
    const int ck = ((tid >> 4) & 3) << 3;

    uint4 arg, brg;
    auto issue = [&](int kt) {
        const int kk = kt << 5;
        const int ga = row0 + cr;
        if (ga < M) arg = *reinterpret_cast<const uint4*>(A + (size_t)ga * K + kk + ck);
        else        arg = make_uint4(0, 0, 0, 0);
        brg = *reinterpret_cast<const uint4*>(Bg + (size_t)(col0 + cr) * K + kk + ck);
    };
    auto commit = [&](int buf) {
        *reinterpret_cast<uint4*>(&Ah[buf][tid * 8]) = arg;
        *reinterpret_cast<uint4*>(&Bh[buf][tid * 8]) = brg;
    };

    f32x4 acc[2][4];
#pragma unroll
    for (int i = 0; i < 2; ++i)
#pragma unroll
        for (int j = 0; j < 4; ++j) acc[i][j] = (f32x4)(0.f);

    issue(0);
    commit(0);
    __syncthreads();

    int cur = 0;
    for (int t = 0; t < nt; ++t) {
        const bool more = (t + 1 < nt);
        if (more) issue(t + 1);

        f16x8 af[2], bf[4];
#pragma unroll
        for (int ii = 0; ii < 2; ++ii)
            af[ii] = ((f16x8*)Ah[cur])[(wr * 2 + ii) * 64 + lane];
#pragma unroll
        for (int jj = 0; jj < 4; ++jj)
            bf[jj] = ((f16x8*)Bh[cur])[(wc * 4 + jj) * 64 + lane];

#pragma unroll
        for (int ii = 0; ii < 2; ++ii)
#pragma unroll
            for (int jj = 0; jj < 4; ++jj)
                acc[ii][jj] = __builtin_amdgcn_mfma_f32_16x16x32_f16(af[ii], bf[jj], acc[ii][jj], 0, 0, 0);

        if (more) {
            commit(cur ^ 1);
            __syncthreads();
        }
        cur ^= 1;
    }

    const int rbase = row0 + wr * 32 + (lane >> 4) * 4;
    const int cbase = col0 + wc * 64 + (lane & 15);
#pragma unroll
    for (int jj = 0; jj < 4; ++jj) {
        const int col = cbase + jj * 16;
        const float bv = bias[col];
#pragma unroll
        for (int ii = 0; ii < 2; ++ii)
#pragma unroll
            for (int r4 = 0; r4 < 4; ++r4) {
                const int row = rbase + ii * 16 + r4;
                if (row >= M) continue;
                C[(size_t)row * N + col] = acc[ii][jj][r4] + bv;
            }
    }
}

// ---------------------------------------------------------------------------
// Fused softmax + sampling. 256 thr = 4 groups of 64; group = one (b,lq).
// Phase 1: 192 (pt,h) setup tasks -> LDS (idx, weight*softmax).
// Phase 2: lane (h, c4) pure gather+FMA.
// Batch->XCD swizzle: batch k owns XCDs {2k, 2k+1}.
// ---------------------------------------------------------------------------
__global__ __launch_bounds__(256)
void msda_sample(const _Float16* __restrict__ v,   // [B][NH][LTOT][32]
                 const _Float16* __restrict__ qo,  // [B*LQ][480] = off|aw
                 const float* __restrict__ refl,   // [B][NQ][NL][NK][2]
                 const float* __restrict__ refr,
                 _Float16* __restrict__ out_pre)   // [B*LQ][256]
{
    // inverse XCD swizzle: bid -> (batch k, block-in-batch j)
    const int bid = blockIdx.x;
    const int xcd = bid & 7;
    const int k   = xcd >> 1;
    const int j   = ((bid >> 3) << 1) | (xcd & 1);
    if (j >= QBPB) return;

    const int g   = threadIdx.x >> 6;
    const int t   = threadIdx.x & 63;
    const int b   = k;
    const int lqi = j * 4 + g;
    const int bq  = b * LQ + lqi;
    const int iq  = lqi / NK;
    const int ik  = lqi - iq * NK;

    __shared__ float s_off[4][384];
    __shared__ float s_aw[4][96];
    __shared__ float s_ref[4][NLVL][4];
    __shared__ int   s_idx[4][192][4];
    __shared__ float s_w[4][192][4];

    // phase 0: load qo + refs
    {
        const _Float16* qop = qo + (size_t)bq * 480;
        for (int i = t; i < 384; i += 64) s_off[g][i] = (float)qop[i];
        for (int i = t; i < 96;  i += 64) s_aw[g][i]  = (float)qop[384 + i];
        if (t < 12) {
            const int nl = t >> 2, comp = t & 3;
            const float* rp = (comp < 2) ? refl : refr;
            s_ref[g][nl][comp] =
                rp[((((size_t)b * NQ + iq) * NLVL + nl) * NK + ik) * 2 + (comp & 1)];
        }
    }
    __syncthreads();

    // phase 0.5: per-head softmax, normalize s_aw in place
    if (t < 8) {
        float mx = -1e30f;
#pragma unroll
        for (int i = 0; i < 12; ++i) mx = fmaxf(mx, s_aw[g][t * 12 + i]);
        float sum = 0.f;
        float e[12];
#pragma unroll
        for (int i = 0; i < 12; ++i) { e[i] = __expf(s_aw[g][t * 12 + i] - mx); sum += e[i]; }
        const float inv = 1.f / sum;
#pragma unroll
        for (int i = 0; i < 12; ++i) s_aw[g][t * 12 + i] = e[i] * inv;
    }
    __syncthreads();

    // phase 1: setup 192 tasks (tau = pt*8 + h)
#pragma unroll
    for (int kk = 0; kk < 3; ++kk) {
        const int tau = kk * 64 + t;
        const int pt = tau >> 3, h = tau & 7;
        const int nl = pt >> 3, p2 = pt & 7, p = p2 & 3, rs = p2 >> 2;
        const int   Wl   = 100 >> nl;
        const int   base = (nl == 0) ? 0 : ((nl == 1) ? 10000 : 12500);
        const float invN = 0.01f * (float)(1 << nl);
        const float fS   = (float)Wl;

        const int ob = ((h * 3 + nl) * 4 + p) * 4 + rs * 2;
        const float ox = s_off[g][ob], oy = s_off[g][ob + 1];
        const float rx = s_ref[g][nl][rs * 2], ry = s_ref[g][nl][rs * 2 + 1];
        const float x = (rx + ox * invN) * fS - 0.5f;
        const float y = (ry + oy * invN) * fS - 0.5f;
        const float x0f = floorf(x), y0f = floorf(y);
        const float tx = x - x0f, ty = y - y0f;
        const int ix = (int)x0f, iy = (int)y0f;
        const float aww = s_aw[g][h * 12 + nl * 4 + p];

        const int x0c = min(max(ix, 0), Wl - 1);
        const int x1c = min(max(ix + 1, 0), Wl - 1);
        const int y0c = min(max(iy, 0), Wl - 1);
        const int y1c = min(max(iy + 1, 0), Wl - 1);
        const float vx0 = (ix     >= 0 && ix     < Wl) ? 1.f : 0.f;
        const float vx1 = (ix + 1 >= 0 && ix + 1 < Wl) ? 1.f : 0.f;
        const float vy0 = (iy     >= 0 && iy     < Wl) ? 1.f : 0.f;
        const float vy1 = (iy + 1 >= 0 && iy + 1 < Wl) ? 1.f : 0.f;

        int4 idx;
        idx.x = (base + y0c * Wl + x0c) * 32;
        idx.y = (base + y0c * Wl + x1c) * 32;
        idx.z = (base + y1c * Wl + x0c) * 32;
        idx.w = (base + y1c * Wl + x1c) * 32;
        float4 wv;
        wv.x = (1.f - tx) * (1.f - ty) * vx0 * vy0 * aww;
        wv.y = tx         * (1.f - ty) * vx1 * vy0 * aww;
        wv.z = (1.f - tx) * ty         * vx0 * vy1 * aww;
        wv.w = tx         * ty         * vx1 * vy1 * aww;

        *reinterpret_cast<int4*>(&s_idx[g][tau][0]) = idx;
        *reinterpret_cast<float4*>(&s_w[g][tau][0]) = wv;
    }
    __syncthreads();

    // phase 2: pure gather + FMA
    const int h  = t >> 3;
    const int c4 = (t & 7) * 4;
    const _Float16* vh = v + ((size_t)(b * NH + h) * LTOT) * 32 + c4;

    float4 acc = make_float4(0.f, 0.f, 0.f, 0.f);
#pragma unroll
    for (int pt = 0; pt < 24; ++pt) {
        const int tau = pt * 8 + h;
        const int4   idx = *reinterpret_cast<const int4*>(&s_idx[g][tau][0]);
        const float4 wv  = *reinterpret_cast<const float4*>(&s_w[g][tau][0]);
        const f16x4 g00 = *reinterpret_cast<const f16x4*>(vh + idx.x);
        const f16x4 g10 = *reinterpret_cast<const f16x4*>(vh + idx.y);
        const f16x4 g01 = *reinterpret_cast<const f16x4*>(vh + idx.z);
        const f16x4 g11 = *reinterpret_cast<const f16x4*>(vh + idx.w);

        acc.x = fmaf(wv.x, (float)g00[0], fmaf(wv.y, (float)g10[0], fmaf(wv.z, (float)g01[0], fmaf(wv.w, (float)g11[0], acc.x))));
        acc.y = fmaf(wv.x, (float)g00[1], fmaf(wv.y, (float)g10[1], fmaf(wv.z, (float)g01[1], fmaf(wv.w, (float)g11[1], acc.y))));
        acc.z = fmaf(wv.x, (float)g00[2], fmaf(wv.y, (float)g10[2], fmaf(wv.z, (float)g01[2], fmaf(wv.w, (float)g11[2], acc.z))));
        acc.w = fmaf(wv.x, (float)g00[3], fmaf(wv.y, (float)g10[3], fmaf(wv.z, (float)g01[3], fmaf(wv.w, (float)g11[3], acc.w))));
    }

    f16x4 o;
    o[0] = (_Float16)acc.x; o[1] = (_Float16)acc.y;
    o[2] = (_Float16)acc.z; o[3] = (_Float16)acc.w;
    *reinterpret_cast<f16x4*>(out_pre + (size_t)bq * EMBED + h * HD + c4) = o;
}

// ---------------------------------------------------------------------------
extern "C" void kernel_launch(void* const* d_in, const int* in_sizes, int n_in,
                              void* d_out, int out_size, void* d_ws, size_t ws_size,
                              hipStream_t stream)
{
    const float* query  = (const float*)d_in[0];
    const float* refl   = (const float*)d_in[1];
    const float* refr   = (const float*)d_in[2];
    const float* value  = (const float*)d_in[3];
    const unsigned char* vmask = (const unsigned char*)d_in[5];
    const float* W_off  = (const float*)d_in[6];
    const float* b_off  = (const float*)d_in[7];
    const float* W_attn = (const float*)d_in[8];
    const float* b_attn = (const float*)d_in[9];
    const float* W_val  = (const float*)d_in[10];
    const float* b_val  = (const float*)d_in[11];
    const float* W_out  = (const float*)d_in[12];
    const float* b_out  = (const float*)d_in[13];

    char* p = (char*)d_ws;
    _Float16* v      = (_Float16*)p;  p += (size_t)MV * 256 * 2;   // head-major
    _Float16* qo     = (_Float16*)p;  p += (size_t)MQ * 480 * 2;
    _Float16* outp   = (_Float16*)p;  p += (size_t)MQ * 256 * 2;
    _Float16* Wv16   = (_Float16*)p;  p += 131072 * 2;
    _Float16* Wqc16  = (_Float16*)p;  p += 122880 * 2;
    _Float16* Wo16   = (_Float16*)p;  p += 65536 * 2;
    float* bqc       = (float*)p;     p += 480 * 4;

    // 0) weights -> fp16 (+ fused qc bias)
    convert_w<<<dim3((CW_TOT + 255) / 256), 256, 0, stream>>>(
        W_val, W_off, W_attn, W_out, b_off, b_attn, Wv16, Wqc16, Wo16, bqc);

    // 1) fused value-proj + qc-proj
    gemm_vq<<<dim3(NBLK_V + NBLK_QC), 512, 0, stream>>>(
        value, Wv16, b_val, v, vmask, query, Wqc16, bqc, qo);

    // 2) fused softmax + sampling (batch->XCD swizzled grid)
    msda_sample<<<dim3(5103), 256, 0, stream>>>(v, qo, refl, refr, outp);

    // 3) output projection
    gemm_out<<<dim3(320), 512, 0, stream>>>(outp, Wo16, b_out, (float*)d_out);
}